// Round 1
// baseline (236.239 us; speedup 1.0000x reference)
//
#include <hip/hip_runtime.h>
#include <math.h>

// ---------------------------------------------------------------------------
// MultiAttention: x[8,1024,512] -> QKV proj -> tridiagonal-band "softmax"
// (off-band score = -1e-9 => closed form over band + uniform tail) -> FC ->
// residual + LayerNorm.  GEMMs in bf16 MFMA (16x16x32), everything else fp32.
// ---------------------------------------------------------------------------

typedef short     s8v  __attribute__((ext_vector_type(8)));   // 8 bf16 (4 VGPR)
typedef float     f4v  __attribute__((ext_vector_type(4)));
typedef unsigned short us4v __attribute__((ext_vector_type(4)));
typedef unsigned short us8v __attribute__((ext_vector_type(8)));

__device__ __forceinline__ unsigned short f2b(float f) {
  union { float f; unsigned int u; } v; v.f = f;
  unsigned int u = v.u;
  return (unsigned short)((u + 0x7fffu + ((u >> 16) & 1u)) >> 16);  // RNE
}

// ---------------- weight convert + transpose: Wt[n][k] = W[k][n] (bf16) ----
__global__ __launch_bounds__(256) void wconv_kernel(
    const float* __restrict__ Wq, const float* __restrict__ Wk,
    const float* __restrict__ Wv, const float* __restrict__ Wfc,
    unsigned short* __restrict__ Wt) {
  __shared__ unsigned short tile[32][33];
  const float* W = (blockIdx.z == 0) ? Wq : (blockIdx.z == 1) ? Wk
                 : (blockIdx.z == 2) ? Wv : Wfc;
  const int tx = threadIdx.x & 31, ty = threadIdx.x >> 5;  // 32 x 8
  const int n0 = blockIdx.x * 32, k0 = blockIdx.y * 32;
  #pragma unroll
  for (int r = ty; r < 32; r += 8)
    tile[r][tx] = f2b(W[(size_t)(k0 + r) * 512 + n0 + tx]);
  __syncthreads();
  unsigned short* dst = Wt + (size_t)blockIdx.z * 512 * 512;
  #pragma unroll
  for (int r = ty; r < 32; r += 8)
    dst[(size_t)(n0 + r) * 512 + k0 + tx] = tile[tx][r];
}

// ---------------- bf16 MFMA GEMM:  C[M,N] = A[M,K] * Bt[N,K]^T -------------
// A fp32 (AF32=1, converted while staging) or bf16 bits (AF32=0).
#define BM 128
#define BN 128
#define BK 32
#define LDT 40   // padded k-stride (ushorts): 80 B, 16B-aligned, 2-way banks

template<int AF32>
__global__ __launch_bounds__(256) void gemm_kernel(
    const void* __restrict__ Aptr, const unsigned short* __restrict__ Bt,
    float* __restrict__ C, int M, int N, int K) {
  __shared__ __align__(16) unsigned short As[BM][LDT];
  __shared__ __align__(16) unsigned short Bs[BN][LDT];
  const int t    = threadIdx.x;
  const int wave = t >> 6, lane = t & 63;
  const int wr   = wave >> 1, wc = wave & 1;
  const int quad = lane >> 4, l16 = lane & 15;
  const int bm = blockIdx.y * BM, bn = blockIdx.x * BN;

  f4v acc[4][4];
  #pragma unroll
  for (int i = 0; i < 4; ++i)
    #pragma unroll
    for (int j = 0; j < 4; ++j) {
      f4v z = {0.f, 0.f, 0.f, 0.f};
      acc[i][j] = z;
    }

  for (int kt = 0; kt < K; kt += BK) {
    // ---- stage A tile (BM x BK) ----
    if (AF32) {
      const float* A = (const float*)Aptr;
      #pragma unroll
      for (int p = 0; p < 4; ++p) {
        int v   = t + 256 * p;        // 0..1023, 4 floats each
        int row = v >> 3;
        int kc  = (v & 7) << 2;
        const float4 f = *(const float4*)(A + (size_t)(bm + row) * K + kt + kc);
        us4v o;
        o[0] = f2b(f.x); o[1] = f2b(f.y); o[2] = f2b(f.z); o[3] = f2b(f.w);
        *(us4v*)&As[row][kc] = o;
      }
    } else {
      const unsigned short* A = (const unsigned short*)Aptr;
      #pragma unroll
      for (int p = 0; p < 2; ++p) {
        int v   = t + 256 * p;        // 0..511, 8 bf16 each
        int row = v >> 2;
        int kc  = (v & 3) << 3;
        *(us8v*)&As[row][kc] =
            *(const us8v*)(A + (size_t)(bm + row) * K + kt + kc);
      }
    }
    // ---- stage B tile (BN x BK) from Bt[N][K] ----
    #pragma unroll
    for (int p = 0; p < 2; ++p) {
      int v  = t + 256 * p;
      int n  = v >> 2;
      int kc = (v & 3) << 3;
      *(us8v*)&Bs[n][kc] =
          *(const us8v*)(Bt + (size_t)(bn + n) * K + kt + kc);
    }
    __syncthreads();

    // ---- MFMA: wave computes 64x64 (4x4 tiles of 16x16) ----
    s8v af[4], bf[4];
    #pragma unroll
    for (int i = 0; i < 4; ++i)
      af[i] = *(const s8v*)&As[wr * 64 + i * 16 + l16][quad * 8];
    #pragma unroll
    for (int j = 0; j < 4; ++j)
      bf[j] = *(const s8v*)&Bs[wc * 64 + j * 16 + l16][quad * 8];
    #pragma unroll
    for (int i = 0; i < 4; ++i)
      #pragma unroll
      for (int j = 0; j < 4; ++j)
        acc[i][j] = __builtin_amdgcn_mfma_f32_16x16x32_bf16(
            af[i], bf[j], acc[i][j], 0, 0, 0);
    __syncthreads();
  }

  // ---- epilogue: C/D layout col=lane&15, row=quad*4+reg ----
  #pragma unroll
  for (int i = 0; i < 4; ++i) {
    int r0 = bm + wr * 64 + i * 16 + quad * 4;
    #pragma unroll
    for (int j = 0; j < 4; ++j) {
      int c0 = bn + wc * 64 + j * 16 + l16;
      #pragma unroll
      for (int r = 0; r < 4; ++r)
        C[(size_t)(r0 + r) * N + c0] = acc[i][j][r];
    }
  }
}

// ---------------- V column sums per (b,h): Vsum[bh][64] --------------------
__global__ __launch_bounds__(256) void vsum_kernel(
    const float* __restrict__ QKV, float* __restrict__ Vsum) {
  const int bh = blockIdx.x;              // 0..63
  const int b = bh >> 3, h = bh & 7;
  const int t = threadIdx.x;
  const int d = t & 63, part = t >> 6;    // 4 partial sums per d
  float s = 0.f;
  const size_t base = ((size_t)b * 1024) * 1536 + 1024 + h * 64 + d;
  for (int k = part; k < 1024; k += 4) s += QKV[base + (size_t)k * 1536];
  __shared__ float red[4][64];
  red[part][d] = s;
  __syncthreads();
  if (part == 0)
    Vsum[bh * 64 + d] = red[0][d] + red[1][d] + red[2][d] + red[3][d];
}

// ---------------- band attention (closed-form softmax tail) ----------------
// scores: band |q-k|<=1 get Q.K/8, everything else -1e-9 (NOT -inf).
__global__ __launch_bounds__(256) void attn_kernel(
    const float* __restrict__ QKV, const float* __restrict__ Vsum,
    unsigned short* __restrict__ ctx) {
  const int bh = blockIdx.x;              // 0..63
  const int b = bh >> 3, h = bh & 7;
  const int chunk = blockIdx.y;           // 0..7 -> 128 queries each
  const int wave = threadIdx.x >> 6, lane = threadIdx.x & 63;
  const int d = lane;
  const float vs = Vsum[bh * 64 + d];
  const size_t rowbase = ((size_t)b * 1024) * 1536 + h * 64 + d;
  const float OFF = -1e-9f;

  for (int qq = 0; qq < 32; ++qq) {
    const int q = chunk * 128 + wave * 32 + qq;
    const float qv = QKV[rowbase + (size_t)q * 1536];
    const size_t kb = rowbase + 512;
    float p0 = qv * QKV[kb + (size_t)q * 1536];
    float pm = (q > 0)    ? qv * QKV[kb + (size_t)(q - 1) * 1536] : 0.f;
    float pp = (q < 1023) ? qv * QKV[kb + (size_t)(q + 1) * 1536] : 0.f;
    #pragma unroll
    for (int off = 32; off > 0; off >>= 1) {   // full-wave butterfly
      pm += __shfl_xor(pm, off);
      p0 += __shfl_xor(p0, off);
      pp += __shfl_xor(pp, off);
    }
    const float s0 = p0 * 0.125f, sm = pm * 0.125f, sp = pp * 0.125f;
    float m = fmaxf(s0, OFF);
    if (q > 0)    m = fmaxf(m, sm);
    if (q < 1023) m = fmaxf(m, sp);
    const float e0   = __expf(s0 - m);
    const float em   = (q > 0)    ? __expf(sm - m) : 0.f;
    const float ep   = (q < 1023) ? __expf(sp - m) : 0.f;
    const int   nb   = 1 + (q > 0) + (q < 1023);
    const float eoff = __expf(OFF - m);
    const float inv  = 1.f / (e0 + em + ep + (float)(1024 - nb) * eoff);
    const size_t vb = rowbase + 1024;
    const float v0 = QKV[vb + (size_t)q * 1536];
    const float vm = (q > 0)    ? QKV[vb + (size_t)(q - 1) * 1536] : 0.f;
    const float vp = (q < 1023) ? QKV[vb + (size_t)(q + 1) * 1536] : 0.f;
    const float c = (em * vm + e0 * v0 + ep * vp + eoff * (vs - vm - v0 - vp)) * inv;
    ctx[((size_t)(b * 1024 + q)) * 512 + h * 64 + d] = f2b(c);
  }
}

// ---------------- residual + LayerNorm over D=512 --------------------------
__global__ __launch_bounds__(256) void ln_kernel(
    const float* __restrict__ outp, const float* __restrict__ x,
    const float* __restrict__ gamma, const float* __restrict__ beta,
    float* __restrict__ y) {
  const int row = blockIdx.x;
  const int t = threadIdx.x;
  const size_t base = (size_t)row * 512;
  const float v0 = outp[base + t] + x[base + t];
  const float v1 = outp[base + t + 256] + x[base + t + 256];
  float s1 = v0 + v1;
  float s2 = v0 * v0 + v1 * v1;
  #pragma unroll
  for (int off = 32; off > 0; off >>= 1) {
    s1 += __shfl_xor(s1, off);
    s2 += __shfl_xor(s2, off);
  }
  __shared__ float r1[4], r2[4];
  const int wave = t >> 6, lane = t & 63;
  if (lane == 0) { r1[wave] = s1; r2[wave] = s2; }
  __syncthreads();
  s1 = r1[0] + r1[1] + r1[2] + r1[3];
  s2 = r2[0] + r2[1] + r2[2] + r2[3];
  const float mu  = s1 * (1.f / 512.f);
  const float var = s2 * (1.f / 512.f) - mu * mu;
  const float rs  = rsqrtf(var + 1e-5f);
  y[base + t]       = (v0 - mu) * rs * gamma[t]       + beta[t];
  y[base + t + 256] = (v1 - mu) * rs * gamma[t + 256] + beta[t + 256];
}

// ---------------------------------------------------------------------------
extern "C" void kernel_launch(void* const* d_in, const int* in_sizes, int n_in,
                              void* d_out, int out_size, void* d_ws, size_t ws_size,
                              hipStream_t stream) {
  const float* x     = (const float*)d_in[0];
  const float* Wq    = (const float*)d_in[1];
  const float* Wk    = (const float*)d_in[2];
  const float* Wv    = (const float*)d_in[3];
  const float* Wfc   = (const float*)d_in[4];
  const float* gamma = (const float*)d_in[5];
  const float* beta  = (const float*)d_in[6];
  float* y = (float*)d_out;

  char* ws = (char*)d_ws;
  // workspace layout (16B-aligned offsets)
  unsigned short* Wt   = (unsigned short*)(ws);                    // 2048*512*2   = 2 MiB
  float*          QKV  = (float*)(ws + 2097152);                   // 8192*1536*4  = 48 MiB
  float*          Vsum = (float*)(ws + 2097152 + 50331648);        // 64*64*4
  unsigned short* ctx  = (unsigned short*)(ws + 52445184);         // 8192*512*2   = 8 MiB
  float*          outb = (float*)(ws + 60833792);                  // 8192*512*4   = 16 MiB

  // 1) weights -> bf16, transposed to [N][K]
  wconv_kernel<<<dim3(16, 16, 4), 256, 0, stream>>>(Wq, Wk, Wv, Wfc, Wt);
  // 2) fused QKV GEMM: [8192,512] x [512,1536] -> QKV fp32
  gemm_kernel<1><<<dim3(1536 / BN, 8192 / BM), 256, 0, stream>>>(
      (const void*)x, Wt, QKV, 8192, 1536, 512);
  // 3) per-(b,h) V column sums
  vsum_kernel<<<64, 256, 0, stream>>>(QKV, Vsum);
  // 4) band attention -> ctx (bf16)
  attn_kernel<<<dim3(64, 8), 256, 0, stream>>>(QKV, Vsum, ctx);
  // 5) FC GEMM: ctx [8192,512] x Wfc [512,512] -> outb fp32
  gemm_kernel<0><<<dim3(512 / BN, 8192 / BM), 256, 0, stream>>>(
      (const void*)ctx, Wt + (size_t)1536 * 512, outb, 8192, 512, 512);
  // 6) residual + LayerNorm
  ln_kernel<<<8192, 256, 0, stream>>>(outb, x, gamma, beta, y);
}

// Round 2
// 179.898 us; speedup vs baseline: 1.3132x; 1.3132x over previous
//
#include <hip/hip_runtime.h>
#include <math.h>

// ---------------------------------------------------------------------------
// MultiAttention: x[8,1024,512] -> QKV proj -> tridiagonal-band "softmax"
// (off-band score = -1e-9 => closed form over band + uniform tail) -> FC ->
// residual + LayerNorm.  GEMMs in bf16 MFMA (16x16x32), everything else fp32.
// ---------------------------------------------------------------------------

typedef short     s8v  __attribute__((ext_vector_type(8)));   // 8 bf16 (4 VGPR)
typedef float     f4v  __attribute__((ext_vector_type(4)));
typedef unsigned short us4v __attribute__((ext_vector_type(4)));
typedef unsigned short us8v __attribute__((ext_vector_type(8)));

__device__ __forceinline__ unsigned short f2b(float f) {
  union { float f; unsigned int u; } v; v.f = f;
  unsigned int u = v.u;
  return (unsigned short)((u + 0x7fffu + ((u >> 16) & 1u)) >> 16);  // RNE
}

// ---------------- weight convert + transpose: Wt[n][k] = W[k][n] (bf16) ----
__global__ __launch_bounds__(256) void wconv_kernel(
    const float* __restrict__ Wq, const float* __restrict__ Wk,
    const float* __restrict__ Wv, const float* __restrict__ Wfc,
    unsigned short* __restrict__ Wt) {
  __shared__ unsigned short tile[32][33];
  const float* W = (blockIdx.z == 0) ? Wq : (blockIdx.z == 1) ? Wk
                 : (blockIdx.z == 2) ? Wv : Wfc;
  const int tx = threadIdx.x & 31, ty = threadIdx.x >> 5;  // 32 x 8
  const int n0 = blockIdx.x * 32, k0 = blockIdx.y * 32;
  #pragma unroll
  for (int r = ty; r < 32; r += 8)
    tile[r][tx] = f2b(W[(size_t)(k0 + r) * 512 + n0 + tx]);
  __syncthreads();
  unsigned short* dst = Wt + (size_t)blockIdx.z * 512 * 512;
  #pragma unroll
  for (int r = ty; r < 32; r += 8)
    dst[(size_t)(n0 + r) * 512 + k0 + tx] = tile[tx][r];
}

// ---------------- bf16 MFMA GEMM:  C[M,N] = A[M,K] * Bt[N,K]^T -------------
// A fp32 (AF32=1, converted while staging) or bf16 bits (AF32=0).
#define BM 128
#define BN 128
#define BK 32
#define LDT 40   // padded k-stride (ushorts): 80 B, 16B-aligned, 2-way banks

template<int AF32>
__global__ __launch_bounds__(256) void gemm_kernel(
    const void* __restrict__ Aptr, const unsigned short* __restrict__ Bt,
    float* __restrict__ C, int M, int N, int K) {
  __shared__ __align__(16) unsigned short As[BM][LDT];
  __shared__ __align__(16) unsigned short Bs[BN][LDT];
  const int t    = threadIdx.x;
  const int wave = t >> 6, lane = t & 63;
  const int wr   = wave >> 1, wc = wave & 1;
  const int quad = lane >> 4, l16 = lane & 15;
  const int bm = blockIdx.y * BM, bn = blockIdx.x * BN;

  f4v acc[4][4];
  #pragma unroll
  for (int i = 0; i < 4; ++i)
    #pragma unroll
    for (int j = 0; j < 4; ++j) {
      f4v z = {0.f, 0.f, 0.f, 0.f};
      acc[i][j] = z;
    }

  for (int kt = 0; kt < K; kt += BK) {
    // ---- stage A tile (BM x BK) ----
    if (AF32) {
      const float* A = (const float*)Aptr;
      #pragma unroll
      for (int p = 0; p < 4; ++p) {
        int v   = t + 256 * p;        // 0..1023, 4 floats each
        int row = v >> 3;
        int kc  = (v & 7) << 2;
        const float4 f = *(const float4*)(A + (size_t)(bm + row) * K + kt + kc);
        us4v o;
        o[0] = f2b(f.x); o[1] = f2b(f.y); o[2] = f2b(f.z); o[3] = f2b(f.w);
        *(us4v*)&As[row][kc] = o;
      }
    } else {
      const unsigned short* A = (const unsigned short*)Aptr;
      #pragma unroll
      for (int p = 0; p < 2; ++p) {
        int v   = t + 256 * p;        // 0..511, 8 bf16 each
        int row = v >> 2;
        int kc  = (v & 3) << 3;
        *(us8v*)&As[row][kc] =
            *(const us8v*)(A + (size_t)(bm + row) * K + kt + kc);
      }
    }
    // ---- stage B tile (BN x BK) from Bt[N][K] ----
    #pragma unroll
    for (int p = 0; p < 2; ++p) {
      int v  = t + 256 * p;
      int n  = v >> 2;
      int kc = (v & 3) << 3;
      *(us8v*)&Bs[n][kc] =
          *(const us8v*)(Bt + (size_t)(bn + n) * K + kt + kc);
    }
    __syncthreads();

    // ---- MFMA: wave computes 64x64 (4x4 tiles of 16x16) ----
    s8v af[4], bf[4];
    #pragma unroll
    for (int i = 0; i < 4; ++i)
      af[i] = *(const s8v*)&As[wr * 64 + i * 16 + l16][quad * 8];
    #pragma unroll
    for (int j = 0; j < 4; ++j)
      bf[j] = *(const s8v*)&Bs[wc * 64 + j * 16 + l16][quad * 8];
    #pragma unroll
    for (int i = 0; i < 4; ++i)
      #pragma unroll
      for (int j = 0; j < 4; ++j)
        acc[i][j] = __builtin_amdgcn_mfma_f32_16x16x32_bf16(
            af[i], bf[j], acc[i][j], 0, 0, 0);
    __syncthreads();
  }

  // ---- epilogue: C/D layout col=lane&15, row=quad*4+reg ----
  #pragma unroll
  for (int i = 0; i < 4; ++i) {
    int r0 = bm + wr * 64 + i * 16 + quad * 4;
    #pragma unroll
    for (int j = 0; j < 4; ++j) {
      int c0 = bn + wc * 64 + j * 16 + l16;
      #pragma unroll
      for (int r = 0; r < 4; ++r)
        C[(size_t)(r0 + r) * N + c0] = acc[i][j][r];
    }
  }
}

// ---------------- V column sums, two-stage coalesced -----------------------
// stage 1: 256 blocks; block = (b, chunk of 32 rows). Coalesced over the
// 512 contiguous V columns (QKV cols 1024..1535). Partials -> part[256][512].
__global__ __launch_bounds__(256) void vsum1_kernel(
    const float* __restrict__ QKV, float* __restrict__ part) {
  const int b = blockIdx.x >> 5;          // 0..7
  const int chunk = blockIdx.x & 31;      // 0..31 (32 rows each)
  const int t = threadIdx.x;
  float s0 = 0.f, s1 = 0.f;
  size_t base = ((size_t)(b * 1024 + chunk * 32)) * 1536 + 1024;
  #pragma unroll 4
  for (int r = 0; r < 32; ++r) {
    s0 += QKV[base + t];
    s1 += QKV[base + t + 256];
    base += 1536;
  }
  float* dst = part + (size_t)blockIdx.x * 512;
  dst[t] = s0;
  dst[t + 256] = s1;
}

// stage 2: 8 blocks; reduce 32 chunk-partials -> Vsum[b*512 + col]
// (same layout as old Vsum[bh*64+d] since col = h*64+d).
__global__ __launch_bounds__(256) void vsum2_kernel(
    const float* __restrict__ part, float* __restrict__ Vsum) {
  const int b = blockIdx.x;
  const int t = threadIdx.x;
  float s0 = 0.f, s1 = 0.f;
  const float* p = part + (size_t)b * 32 * 512;
  #pragma unroll
  for (int c = 0; c < 32; ++c) {
    s0 += p[(size_t)c * 512 + t];
    s1 += p[(size_t)c * 512 + t + 256];
  }
  Vsum[b * 512 + t] = s0;
  Vsum[b * 512 + t + 256] = s1;
}

// ---------------- band attention (closed-form softmax tail) ----------------
// scores: band |q-k|<=1 get Q.K/8, everything else -1e-9 (NOT -inf).
__global__ __launch_bounds__(256) void attn_kernel(
    const float* __restrict__ QKV, const float* __restrict__ Vsum,
    unsigned short* __restrict__ ctx) {
  const int bh = blockIdx.x;              // 0..63
  const int b = bh >> 3, h = bh & 7;
  const int chunk = blockIdx.y;           // 0..7 -> 128 queries each
  const int wave = threadIdx.x >> 6, lane = threadIdx.x & 63;
  const int d = lane;
  const float vs = Vsum[bh * 64 + d];
  const size_t rowbase = ((size_t)b * 1024) * 1536 + h * 64 + d;
  const float OFF = -1e-9f;

  for (int qq = 0; qq < 32; ++qq) {
    const int q = chunk * 128 + wave * 32 + qq;
    const float qv = QKV[rowbase + (size_t)q * 1536];
    const size_t kb = rowbase + 512;
    float p0 = qv * QKV[kb + (size_t)q * 1536];
    float pm = (q > 0)    ? qv * QKV[kb + (size_t)(q - 1) * 1536] : 0.f;
    float pp = (q < 1023) ? qv * QKV[kb + (size_t)(q + 1) * 1536] : 0.f;
    #pragma unroll
    for (int off = 32; off > 0; off >>= 1) {   // full-wave butterfly
      pm += __shfl_xor(pm, off);
      p0 += __shfl_xor(p0, off);
      pp += __shfl_xor(pp, off);
    }
    const float s0 = p0 * 0.125f, sm = pm * 0.125f, sp = pp * 0.125f;
    float m = fmaxf(s0, OFF);
    if (q > 0)    m = fmaxf(m, sm);
    if (q < 1023) m = fmaxf(m, sp);
    const float e0   = __expf(s0 - m);
    const float em   = (q > 0)    ? __expf(sm - m) : 0.f;
    const float ep   = (q < 1023) ? __expf(sp - m) : 0.f;
    const int   nb   = 1 + (q > 0) + (q < 1023);
    const float eoff = __expf(OFF - m);
    const float inv  = 1.f / (e0 + em + ep + (float)(1024 - nb) * eoff);
    const size_t vb = rowbase + 1024;
    const float v0 = QKV[vb + (size_t)q * 1536];
    const float vm = (q > 0)    ? QKV[vb + (size_t)(q - 1) * 1536] : 0.f;
    const float vp = (q < 1023) ? QKV[vb + (size_t)(q + 1) * 1536] : 0.f;
    const float c = (em * vm + e0 * v0 + ep * vp + eoff * (vs - vm - v0 - vp)) * inv;
    ctx[((size_t)(b * 1024 + q)) * 512 + h * 64 + d] = f2b(c);
  }
}

// ---------------- residual + LayerNorm over D=512 --------------------------
__global__ __launch_bounds__(256) void ln_kernel(
    const float* __restrict__ outp, const float* __restrict__ x,
    const float* __restrict__ gamma, const float* __restrict__ beta,
    float* __restrict__ y) {
  const int row = blockIdx.x;
  const int t = threadIdx.x;
  const size_t base = (size_t)row * 512;
  const float v0 = outp[base + t] + x[base + t];
  const float v1 = outp[base + t + 256] + x[base + t + 256];
  float s1 = v0 + v1;
  float s2 = v0 * v0 + v1 * v1;
  #pragma unroll
  for (int off = 32; off > 0; off >>= 1) {
    s1 += __shfl_xor(s1, off);
    s2 += __shfl_xor(s2, off);
  }
  __shared__ float r1[4], r2[4];
  const int wave = t >> 6, lane = t & 63;
  if (lane == 0) { r1[wave] = s1; r2[wave] = s2; }
  __syncthreads();
  s1 = r1[0] + r1[1] + r1[2] + r1[3];
  s2 = r2[0] + r2[1] + r2[2] + r2[3];
  const float mu  = s1 * (1.f / 512.f);
  const float var = s2 * (1.f / 512.f) - mu * mu;
  const float rs  = rsqrtf(var + 1e-5f);
  y[base + t]       = (v0 - mu) * rs * gamma[t]       + beta[t];
  y[base + t + 256] = (v1 - mu) * rs * gamma[t + 256] + beta[t + 256];
}

// ---------------------------------------------------------------------------
extern "C" void kernel_launch(void* const* d_in, const int* in_sizes, int n_in,
                              void* d_out, int out_size, void* d_ws, size_t ws_size,
                              hipStream_t stream) {
  const float* x     = (const float*)d_in[0];
  const float* Wq    = (const float*)d_in[1];
  const float* Wk    = (const float*)d_in[2];
  const float* Wv    = (const float*)d_in[3];
  const float* Wfc   = (const float*)d_in[4];
  const float* gamma = (const float*)d_in[5];
  const float* beta  = (const float*)d_in[6];
  float* y = (float*)d_out;

  char* ws = (char*)d_ws;
  // workspace layout (16B-aligned offsets)
  unsigned short* Wt   = (unsigned short*)(ws);                    // 2048*512*2   = 2 MiB
  float*          QKV  = (float*)(ws + 2097152);                   // 8192*1536*4  = 48 MiB
  float*          Vsum = (float*)(ws + 2097152 + 50331648);        // 8*512*4
  unsigned short* ctx  = (unsigned short*)(ws + 52445184);         // 8192*512*2   = 8 MiB
  float*          outb = (float*)(ws + 60833792);                  // 8192*512*4   = 16 MiB
  float*          vpar = outb;  // reuse outb region for vsum partials (512 KiB),
                                // consumed by vsum2 before GEMM2 writes outb.

  // 1) weights -> bf16, transposed to [N][K]
  wconv_kernel<<<dim3(16, 16, 4), 256, 0, stream>>>(Wq, Wk, Wv, Wfc, Wt);
  // 2) fused QKV GEMM: [8192,512] x [512,1536] -> QKV fp32
  gemm_kernel<1><<<dim3(1536 / BN, 8192 / BM), 256, 0, stream>>>(
      (const void*)x, Wt, QKV, 8192, 1536, 512);
  // 3) per-(b,h) V column sums (two-stage, coalesced)
  vsum1_kernel<<<256, 256, 0, stream>>>(QKV, vpar);
  vsum2_kernel<<<8, 256, 0, stream>>>(vpar, Vsum);
  // 4) band attention -> ctx (bf16)
  attn_kernel<<<dim3(64, 8), 256, 0, stream>>>(QKV, Vsum, ctx);
  // 5) FC GEMM: ctx [8192,512] x Wfc [512,512] -> outb fp32
  gemm_kernel<0><<<dim3(512 / BN, 8192 / BM), 256, 0, stream>>>(
      (const void*)ctx, Wt + (size_t)1536 * 512, outb, 8192, 512, 512);
  // 6) residual + LayerNorm
  ln_kernel<<<8192, 256, 0, stream>>>(outb, x, gamma, beta, y);
}

// Round 3
// 147.693 us; speedup vs baseline: 1.5995x; 1.2181x over previous
//
#include <hip/hip_runtime.h>
#include <math.h>

// ---------------------------------------------------------------------------
// MultiAttention: x[8,1024,512] -> QKV proj (bf16 MFMA) -> tridiagonal-band
// "softmax" (off-band score = -1e-9 => closed form: uniform tail + 3-term
// band correction) -> FC (bf16 MFMA) -> residual + LayerNorm (fp32).
// Pipeline is bf16-resident between GEMMs; residual/LN in fp32.
// ---------------------------------------------------------------------------

typedef short     s8v  __attribute__((ext_vector_type(8)));   // 8 bf16 (4 VGPR)
typedef float     f4v  __attribute__((ext_vector_type(4)));
typedef unsigned short us4v __attribute__((ext_vector_type(4)));
typedef unsigned short us8v __attribute__((ext_vector_type(8)));

__device__ __forceinline__ unsigned short f2b(float f) {
  union { float f; unsigned int u; } v; v.f = f;
  unsigned int u = v.u;
  return (unsigned short)((u + 0x7fffu + ((u >> 16) & 1u)) >> 16);  // RNE
}
__device__ __forceinline__ float b2f(unsigned short u) {
  union { unsigned int i; float f; } v; v.i = ((unsigned int)u) << 16;
  return v.f;
}

// ---------------- weight convert + transpose: Wt[n][k] = W[k][n] (bf16) ----
__global__ __launch_bounds__(256) void wconv_kernel(
    const float* __restrict__ Wq, const float* __restrict__ Wk,
    const float* __restrict__ Wv, const float* __restrict__ Wfc,
    unsigned short* __restrict__ Wt) {
  __shared__ unsigned short tile[32][33];
  const float* W = (blockIdx.z == 0) ? Wq : (blockIdx.z == 1) ? Wk
                 : (blockIdx.z == 2) ? Wv : Wfc;
  const int tx = threadIdx.x & 31, ty = threadIdx.x >> 5;  // 32 x 8
  const int n0 = blockIdx.x * 32, k0 = blockIdx.y * 32;
  #pragma unroll
  for (int r = ty; r < 32; r += 8)
    tile[r][tx] = f2b(W[(size_t)(k0 + r) * 512 + n0 + tx]);
  __syncthreads();
  unsigned short* dst = Wt + (size_t)blockIdx.z * 512 * 512;
  #pragma unroll
  for (int r = ty; r < 32; r += 8)
    dst[(size_t)(n0 + r) * 512 + k0 + tx] = tile[tx][r];
}

// ---------------- x -> bf16 ------------------------------------------------
__global__ __launch_bounds__(256) void xconv_kernel(
    const float* __restrict__ x, unsigned short* __restrict__ xb) {
  const int i = blockIdx.x * 256 + threadIdx.x;   // 1 float4 each
  const float4 f = ((const float4*)x)[i];
  us4v o; o[0] = f2b(f.x); o[1] = f2b(f.y); o[2] = f2b(f.z); o[3] = f2b(f.w);
  ((us4v*)xb)[i] = o;
}

// ---------------- bf16 MFMA GEMM:  C[M,N] = A[M,K] * Bt[N,K]^T -------------
// A bf16 [M][K]; C fp32 (OUTBF=0) or bf16 (OUTBF=1).
#define BM 128
#define BN 128
#define BK 32
#define LDT 40   // padded k-stride (ushorts): 80 B, 16B-aligned, 2-way banks

template<int OUTBF>
__global__ __launch_bounds__(256) void gemm_kernel(
    const unsigned short* __restrict__ A, const unsigned short* __restrict__ Bt,
    void* __restrict__ Cv, int M, int N, int K) {
  __shared__ __align__(16) unsigned short As[BM][LDT];
  __shared__ __align__(16) unsigned short Bs[BN][LDT];
  const int t    = threadIdx.x;
  const int wave = t >> 6, lane = t & 63;
  const int wr   = wave >> 1, wc = wave & 1;
  const int quad = lane >> 4, l16 = lane & 15;
  const int bm = blockIdx.y * BM, bn = blockIdx.x * BN;

  f4v acc[4][4];
  #pragma unroll
  for (int i = 0; i < 4; ++i)
    #pragma unroll
    for (int j = 0; j < 4; ++j) {
      f4v z = {0.f, 0.f, 0.f, 0.f};
      acc[i][j] = z;
    }

  for (int kt = 0; kt < K; kt += BK) {
    #pragma unroll
    for (int p = 0; p < 2; ++p) {
      int v   = t + 256 * p;        // 0..511, 8 bf16 each
      int row = v >> 2;
      int kc  = (v & 3) << 3;
      *(us8v*)&As[row][kc] =
          *(const us8v*)(A + (size_t)(bm + row) * K + kt + kc);
      *(us8v*)&Bs[row][kc] =
          *(const us8v*)(Bt + (size_t)(bn + row) * K + kt + kc);
    }
    __syncthreads();

    s8v af[4], bf[4];
    #pragma unroll
    for (int i = 0; i < 4; ++i)
      af[i] = *(const s8v*)&As[wr * 64 + i * 16 + l16][quad * 8];
    #pragma unroll
    for (int j = 0; j < 4; ++j)
      bf[j] = *(const s8v*)&Bs[wc * 64 + j * 16 + l16][quad * 8];
    #pragma unroll
    for (int i = 0; i < 4; ++i)
      #pragma unroll
      for (int j = 0; j < 4; ++j)
        acc[i][j] = __builtin_amdgcn_mfma_f32_16x16x32_bf16(
            af[i], bf[j], acc[i][j], 0, 0, 0);
    __syncthreads();
  }

  // C/D layout: col = lane&15, row = quad*4 + reg
  #pragma unroll
  for (int i = 0; i < 4; ++i) {
    int r0 = bm + wr * 64 + i * 16 + quad * 4;
    #pragma unroll
    for (int j = 0; j < 4; ++j) {
      int c0 = bn + wc * 64 + j * 16 + l16;
      #pragma unroll
      for (int r = 0; r < 4; ++r) {
        if (OUTBF)
          ((unsigned short*)Cv)[(size_t)(r0 + r) * N + c0] = f2b(acc[i][j][r]);
        else
          ((float*)Cv)[(size_t)(r0 + r) * N + c0] = acc[i][j][r];
      }
    }
  }
}

// ---------------- V column sums, two-stage coalesced (bf16 input) ----------
// stage 1: 512 blocks; block = (b, chunk of 16 rows); thread sums 2 adjacent
// V columns (read as one uint). part[blk][512] fp32.
__global__ __launch_bounds__(256) void vsum1_kernel(
    const unsigned short* __restrict__ QKV, float* __restrict__ part) {
  const int b = blockIdx.x >> 6;          // 0..7
  const int chunk = blockIdx.x & 63;      // 0..63 (16 rows each)
  const int t = threadIdx.x;
  float s0 = 0.f, s1 = 0.f;
  const unsigned short* p =
      QKV + ((size_t)(b * 1024 + chunk * 16)) * 1536 + 1024 + 2 * t;
  #pragma unroll 4
  for (int r = 0; r < 16; ++r) {
    const unsigned int w = *(const unsigned int*)p;
    s0 += b2f((unsigned short)(w & 0xffffu));
    s1 += b2f((unsigned short)(w >> 16));
    p += 1536;
  }
  float2 o; o.x = s0; o.y = s1;
  *(float2*)&part[(size_t)blockIdx.x * 512 + 2 * t] = o;
}

// stage 2: 8 blocks; reduce 64 chunk-partials -> Vsum[b*512 + col]
__global__ __launch_bounds__(256) void vsum2_kernel(
    const float* __restrict__ part, float* __restrict__ Vsum) {
  const int b = blockIdx.x;
  const int t = threadIdx.x;
  float s0 = 0.f, s1 = 0.f;
  const float* p = part + (size_t)b * 64 * 512;
  #pragma unroll
  for (int c = 0; c < 64; ++c) {
    s0 += p[(size_t)c * 512 + t];
    s1 += p[(size_t)c * 512 + t + 256];
  }
  Vsum[b * 512 + t] = s0;
  Vsum[b * 512 + t + 256] = s1;
}

// ---------------- band attention (closed-form softmax tail) ----------------
// block = (bh, 128-query chunk); 256 threads = 2 per query (d-halves).
// K/V tiles (130 rows x 64) staged in LDS (stride 68 ushorts => <=4-way
// b64 bank conflicts). Q read direct from global. One shfl_xor(1) per dot.
#define KVS 68
__global__ __launch_bounds__(256) void attn_kernel(
    const unsigned short* __restrict__ QKV, const float* __restrict__ Vsum,
    unsigned short* __restrict__ ctx) {
  __shared__ __align__(16) unsigned short Ks[130 * KVS];
  __shared__ __align__(16) unsigned short Vs[130 * KVS];
  __shared__ __align__(16) float vs_s[64];
  const int bh = blockIdx.x;              // 0..63
  const int b = bh >> 3, h = bh & 7;
  const int q0 = blockIdx.y * 128;        // 0..896
  const int t = threadIdx.x;
  const size_t rowb = ((size_t)b * 1024) * 1536;

  // stage K/V rows q0-1 .. q0+128 (clamped)
  #pragma unroll
  for (int p = 0; p < 5; ++p) {
    const int i = p * 32 + (t >> 3);
    if (i < 130) {
      int g = q0 - 1 + i;
      g = g < 0 ? 0 : (g > 1023 ? 1023 : g);
      const unsigned short* src =
          QKV + rowb + (size_t)g * 1536 + h * 64 + (t & 7) * 8;
      const us8v kv = *(const us8v*)(src + 512);
      const us8v vv = *(const us8v*)(src + 1024);
      us4v lo, hi;
      #pragma unroll
      for (int r = 0; r < 4; ++r) { lo[r] = kv[r]; hi[r] = kv[r + 4]; }
      *(us4v*)&Ks[i * KVS + (t & 7) * 8]     = lo;
      *(us4v*)&Ks[i * KVS + (t & 7) * 8 + 4] = hi;
      #pragma unroll
      for (int r = 0; r < 4; ++r) { lo[r] = vv[r]; hi[r] = vv[r + 4]; }
      *(us4v*)&Vs[i * KVS + (t & 7) * 8]     = lo;
      *(us4v*)&Vs[i * KVS + (t & 7) * 8 + 4] = hi;
    }
  }
  if (t < 64) vs_s[t] = Vsum[(b << 9) + h * 64 + t];
  __syncthreads();

  const int q    = q0 + (t >> 1);
  const int half = t & 1;
  const int li   = (t >> 1) + 1;          // LDS row of key/value q
  const int co   = half * 32;             // this thread's d-offset

  // ---- phase 1: partial dots over 32 dims, pair-combine via shfl ----
  float pm = 0.f, p0 = 0.f, pp = 0.f;
  const unsigned short* Qp = QKV + rowb + (size_t)q * 1536 + h * 64 + co;
  const us8v qa = *(const us8v*)(Qp);
  const us8v qb = *(const us8v*)(Qp + 8);
  const us8v qc = *(const us8v*)(Qp + 16);
  const us8v qd = *(const us8v*)(Qp + 24);
  #pragma unroll
  for (int jj = 0; jj < 8; ++jj) {
    const us4v km = *(const us4v*)&Ks[(li - 1) * KVS + co + jj * 4];
    const us4v k0 = *(const us4v*)&Ks[li * KVS + co + jj * 4];
    const us4v kp = *(const us4v*)&Ks[(li + 1) * KVS + co + jj * 4];
    #pragma unroll
    for (int r = 0; r < 4; ++r) {
      const int e = jj * 4 + r;
      const unsigned short qu = (e < 8) ? qa[e & 7] : (e < 16) ? qb[e & 7]
                              : (e < 24) ? qc[e & 7] : qd[e & 7];
      const float qf = b2f(qu);
      pm += qf * b2f(km[r]);
      p0 += qf * b2f(k0[r]);
      pp += qf * b2f(kp[r]);
    }
  }
  pm += __shfl_xor(pm, 1);
  p0 += __shfl_xor(p0, 1);
  pp += __shfl_xor(pp, 1);

  // ---- softmax weights (uniform tail) ----
  const float OFF = -1e-9f;
  const float s0 = p0 * 0.125f;
  const float sm = (q > 0)    ? pm * 0.125f : OFF;   // em==eoff at edge
  const float sp = (q < 1023) ? pp * 0.125f : OFF;
  const float m  = fmaxf(fmaxf(s0, sm), fmaxf(sp, OFF));
  const float e0 = __expf(s0 - m), em = __expf(sm - m), ep = __expf(sp - m);
  const float eoff = __expf(OFF - m);
  const float inv  = 1.f / (e0 + em + ep + 1021.f * eoff);
  const float wm = (em - eoff) * inv, w0 = (e0 - eoff) * inv,
              wp = (ep - eoff) * inv, wt = eoff * inv;

  // ---- phase 2: ctx = wt*Vsum + wm*Vm + w0*V0 + wp*Vp ----
  unsigned short* cp = ctx + ((size_t)(b * 1024 + q)) * 512 + h * 64 + co;
  #pragma unroll
  for (int jj = 0; jj < 8; ++jj) {
    const us4v a  = *(const us4v*)&Vs[(li - 1) * KVS + co + jj * 4];
    const us4v v0 = *(const us4v*)&Vs[li * KVS + co + jj * 4];
    const us4v c  = *(const us4v*)&Vs[(li + 1) * KVS + co + jj * 4];
    const float4 vsv = *(const float4*)&vs_s[co + jj * 4];
    us4v o;
    o[0] = f2b(wt * vsv.x + wm * b2f(a[0]) + w0 * b2f(v0[0]) + wp * b2f(c[0]));
    o[1] = f2b(wt * vsv.y + wm * b2f(a[1]) + w0 * b2f(v0[1]) + wp * b2f(c[1]));
    o[2] = f2b(wt * vsv.z + wm * b2f(a[2]) + w0 * b2f(v0[2]) + wp * b2f(c[2]));
    o[3] = f2b(wt * vsv.w + wm * b2f(a[3]) + w0 * b2f(v0[3]) + wp * b2f(c[3]));
    *(us4v*)(cp + jj * 4) = o;
  }
}

// ---------------- residual + LayerNorm over D=512 --------------------------
__global__ __launch_bounds__(256) void ln_kernel(
    const float* __restrict__ outp, const float* __restrict__ x,
    const float* __restrict__ gamma, const float* __restrict__ beta,
    float* __restrict__ y) {
  const int row = blockIdx.x;
  const int t = threadIdx.x;
  const size_t base = (size_t)row * 512;
  const float v0 = outp[base + t] + x[base + t];
  const float v1 = outp[base + t + 256] + x[base + t + 256];
  float s1 = v0 + v1;
  float s2 = v0 * v0 + v1 * v1;
  #pragma unroll
  for (int off = 32; off > 0; off >>= 1) {
    s1 += __shfl_xor(s1, off);
    s2 += __shfl_xor(s2, off);
  }
  __shared__ float r1[4], r2[4];
  const int wave = t >> 6, lane = t & 63;
  if (lane == 0) { r1[wave] = s1; r2[wave] = s2; }
  __syncthreads();
  s1 = r1[0] + r1[1] + r1[2] + r1[3];
  s2 = r2[0] + r2[1] + r2[2] + r2[3];
  const float mu  = s1 * (1.f / 512.f);
  const float var = s2 * (1.f / 512.f) - mu * mu;
  const float rs  = rsqrtf(var + 1e-5f);
  y[base + t]       = (v0 - mu) * rs * gamma[t]       + beta[t];
  y[base + t + 256] = (v1 - mu) * rs * gamma[t + 256] + beta[t + 256];
}

// ---------------------------------------------------------------------------
extern "C" void kernel_launch(void* const* d_in, const int* in_sizes, int n_in,
                              void* d_out, int out_size, void* d_ws, size_t ws_size,
                              hipStream_t stream) {
  const float* x     = (const float*)d_in[0];
  const float* Wq    = (const float*)d_in[1];
  const float* Wk    = (const float*)d_in[2];
  const float* Wv    = (const float*)d_in[3];
  const float* Wfc   = (const float*)d_in[4];
  const float* gamma = (const float*)d_in[5];
  const float* beta  = (const float*)d_in[6];
  float* y = (float*)d_out;

  char* ws = (char*)d_ws;
  unsigned short* Wt   = (unsigned short*)(ws);              // 2 MiB
  unsigned short* xb   = (unsigned short*)(ws + 2097152);    // 8 MiB
  unsigned short* QKV  = (unsigned short*)(ws + 10485760);   // 24 MiB
  float*          Vsum = (float*)(ws + 35651584);            // 16 KiB
  unsigned short* ctx  = (unsigned short*)(ws + 35667968);   // 8 MiB
  float*          outb = (float*)(ws + 44056576);            // 16 MiB
  float*          vpar = outb;  // 1 MiB partials, consumed before GEMM2

  // 1) weights -> bf16, transposed to [N][K]; x -> bf16
  wconv_kernel<<<dim3(16, 16, 4), 256, 0, stream>>>(Wq, Wk, Wv, Wfc, Wt);
  xconv_kernel<<<4096, 256, 0, stream>>>(x, xb);
  // 2) fused QKV GEMM -> bf16 QKV [8192][1536]
  gemm_kernel<1><<<dim3(1536 / BN, 8192 / BM), 256, 0, stream>>>(
      xb, Wt, (void*)QKV, 8192, 1536, 512);
  // 3) V column sums
  vsum1_kernel<<<512, 256, 0, stream>>>(QKV, vpar);
  vsum2_kernel<<<8, 256, 0, stream>>>(vpar, Vsum);
  // 4) band attention -> ctx (bf16)
  attn_kernel<<<dim3(64, 8), 256, 0, stream>>>(QKV, Vsum, ctx);
  // 5) FC GEMM: ctx [8192,512] x Wfc^T -> outb fp32
  gemm_kernel<0><<<dim3(512 / BN, 8192 / BM), 256, 0, stream>>>(
      ctx, Wt + (size_t)1536 * 512, (void*)outb, 8192, 512, 512);
  // 6) residual + LayerNorm
  ln_kernel<<<8192, 256, 0, stream>>>(outb, x, gamma, beta, y);
}

// Round 4
// 146.931 us; speedup vs baseline: 1.6078x; 1.0052x over previous
//
#include <hip/hip_runtime.h>
#include <math.h>

// ---------------------------------------------------------------------------
// MultiAttention: x[8,1024,512] -> QKV proj (bf16 MFMA) -> tridiagonal-band
// "softmax" (off-band score = -1e-9 => closed form: uniform tail + 3-term
// band correction) -> FC (bf16 MFMA) -> residual + LayerNorm (fp32).
// GEMMs: global_load_lds dwordx4 staging (wave-uniform dest, XOR-swizzled
// source so fragment ds_read_b128 is 2-way/bank = free), m97-style K-loop.
// ---------------------------------------------------------------------------

typedef short     s8v  __attribute__((ext_vector_type(8)));   // 8 bf16 (4 VGPR)
typedef float     f4v  __attribute__((ext_vector_type(4)));
typedef unsigned short us4v __attribute__((ext_vector_type(4)));
typedef unsigned short us8v __attribute__((ext_vector_type(8)));

__device__ __forceinline__ unsigned short f2b(float f) {
  union { float f; unsigned int u; } v; v.f = f;
  unsigned int u = v.u;
  return (unsigned short)((u + 0x7fffu + ((u >> 16) & 1u)) >> 16);  // RNE
}
__device__ __forceinline__ float b2f(unsigned short u) {
  union { unsigned int i; float f; } v; v.i = ((unsigned int)u) << 16;
  return v.f;
}
__device__ __forceinline__ void gload_lds16(const void* g, void* l) {
  __builtin_amdgcn_global_load_lds(
      (const __attribute__((address_space(1))) void*)g,
      (__attribute__((address_space(3))) void*)l, 16, 0, 0);
}

// ---------------- weight convert + transpose: Wt[n][k] = W[k][n] (bf16) ----
__global__ __launch_bounds__(256) void wconv_kernel(
    const float* __restrict__ Wq, const float* __restrict__ Wk,
    const float* __restrict__ Wv, const float* __restrict__ Wfc,
    unsigned short* __restrict__ Wt) {
  __shared__ unsigned short tile[32][33];
  const float* W = (blockIdx.z == 0) ? Wq : (blockIdx.z == 1) ? Wk
                 : (blockIdx.z == 2) ? Wv : Wfc;
  const int tx = threadIdx.x & 31, ty = threadIdx.x >> 5;  // 32 x 8
  const int n0 = blockIdx.x * 32, k0 = blockIdx.y * 32;
  #pragma unroll
  for (int r = ty; r < 32; r += 8)
    tile[r][tx] = f2b(W[(size_t)(k0 + r) * 512 + n0 + tx]);
  __syncthreads();
  unsigned short* dst = Wt + (size_t)blockIdx.z * 512 * 512;
  #pragma unroll
  for (int r = ty; r < 32; r += 8)
    dst[(size_t)(n0 + r) * 512 + k0 + tx] = tile[tx][r];
}

// ---------------- x -> bf16 ------------------------------------------------
__global__ __launch_bounds__(256) void xconv_kernel(
    const float* __restrict__ x, unsigned short* __restrict__ xb) {
  const int i = blockIdx.x * 256 + threadIdx.x;   // 1 float4 each
  const float4 f = ((const float4*)x)[i];
  us4v o; o[0] = f2b(f.x); o[1] = f2b(f.y); o[2] = f2b(f.z); o[3] = f2b(f.w);
  ((us4v*)xb)[i] = o;
}

// ---------------- bf16 MFMA GEMM:  C[M,N] = A[M,K] * Bt[N,K]^T -------------
// A bf16 [M][K]; C fp32 (OUTBF=0) or bf16 (OUTBF=1, LDS-bounce epilogue).
// LDS tiles unpadded 128x32; chunk (16B) at index r*4+c holds global k-chunk
// c ^ ((r>>1)&3) of row r  => fragment reads are 2-way-bank (free).
#define BM 128
#define BN 128
#define BK 32

template<int OUTBF>
__global__ __launch_bounds__(256) void gemm_kernel(
    const unsigned short* __restrict__ A, const unsigned short* __restrict__ Bt,
    void* __restrict__ Cv, int M, int N, int K) {
  __shared__ __align__(16) unsigned short smem[OUTBF ? 16384 : 8192];
  unsigned short* As = smem;          // 4096 ushorts = 128x32
  unsigned short* Bs = smem + 4096;
  const int t    = threadIdx.x;
  const int wave = t >> 6, lane = t & 63;
  const int wr   = wave >> 1, wc = wave & 1;
  const int quad = lane >> 4, l16 = lane & 15;
  const int bm = blockIdx.y * BM, bn = blockIdx.x * BN;

  // staging: 512 chunks per tile; wave w -> chunks [w*128, w*128+128), 2 issues
  const int ci0 = wave * 128 + lane, ci1 = ci0 + 64;
  const int r0 = ci0 >> 2, c0 = (ci0 & 3) ^ ((r0 >> 1) & 3);
  const int r1 = ci1 >> 2, c1 = (ci1 & 3) ^ ((r1 >> 1) & 3);
  const unsigned short* ga0 = A  + (size_t)(bm + r0) * K + c0 * 8;
  const unsigned short* ga1 = A  + (size_t)(bm + r1) * K + c1 * 8;
  const unsigned short* gb0 = Bt + (size_t)(bn + r0) * K + c0 * 8;
  const unsigned short* gb1 = Bt + (size_t)(bn + r1) * K + c1 * 8;
  unsigned short* la0 = As + wave * 1024;        // wave-uniform dests
  unsigned short* la1 = As + wave * 1024 + 512;
  unsigned short* lb0 = Bs + wave * 1024;
  unsigned short* lb1 = Bs + wave * 1024 + 512;

  const int sw = (l16 >> 1) & 3;   // fragment-read swizzle

  f4v acc[4][4];
  #pragma unroll
  for (int i = 0; i < 4; ++i)
    #pragma unroll
    for (int j = 0; j < 4; ++j) {
      f4v z = {0.f, 0.f, 0.f, 0.f};
      acc[i][j] = z;
    }

  for (int kt = 0; kt < K; kt += BK) {
    gload_lds16(ga0 + kt, la0);
    gload_lds16(ga1 + kt, la1);
    gload_lds16(gb0 + kt, lb0);
    gload_lds16(gb1 + kt, lb1);
    __syncthreads();   // drains vmcnt (global_load_lds) for all waves

    s8v af[4], bf[4];
    #pragma unroll
    for (int i = 0; i < 4; ++i) {
      const int r = wr * 64 + i * 16 + l16;
      af[i] = *(const s8v*)&As[(r * 4 + (quad ^ sw)) * 8];
    }
    #pragma unroll
    for (int j = 0; j < 4; ++j) {
      const int r = wc * 64 + j * 16 + l16;
      bf[j] = *(const s8v*)&Bs[(r * 4 + (quad ^ sw)) * 8];
    }
    #pragma unroll
    for (int i = 0; i < 4; ++i)
      #pragma unroll
      for (int j = 0; j < 4; ++j)
        acc[i][j] = __builtin_amdgcn_mfma_f32_16x16x32_bf16(
            af[i], bf[j], acc[i][j], 0, 0, 0);
    __syncthreads();   // LDS reads done before next iter's DMA overwrites
  }

  // C/D layout: col = lane&15, row = quad*4 + reg
  if (OUTBF) {
    // bounce through LDS (32 KB) -> fully coalesced 16B stores
    #pragma unroll
    for (int i = 0; i < 4; ++i) {
      const int lr0 = wr * 64 + i * 16 + quad * 4;
      #pragma unroll
      for (int j = 0; j < 4; ++j) {
        const int lc = wc * 64 + j * 16 + l16;
        #pragma unroll
        for (int r = 0; r < 4; ++r)
          smem[(lr0 + r) * 128 + lc] = f2b(acc[i][j][r]);
      }
    }
    __syncthreads();
    unsigned short* Cb = (unsigned short*)Cv;
    #pragma unroll
    for (int p = 0; p < 8; ++p) {
      const int row = p * 16 + (t >> 4);
      const int ch  = t & 15;
      *(us8v*)(Cb + (size_t)(bm + row) * N + bn + ch * 8) =
          *(const us8v*)&smem[row * 128 + ch * 8];
    }
  } else {
    float* C = (float*)Cv;
    #pragma unroll
    for (int i = 0; i < 4; ++i) {
      const int gr0 = bm + wr * 64 + i * 16 + quad * 4;
      #pragma unroll
      for (int j = 0; j < 4; ++j) {
        const int gc = bn + wc * 64 + j * 16 + l16;
        #pragma unroll
        for (int r = 0; r < 4; ++r)
          C[(size_t)(gr0 + r) * N + gc] = acc[i][j][r];
      }
    }
  }
}

// ---------------- V column sums, two-stage coalesced (bf16 input) ----------
__global__ __launch_bounds__(256) void vsum1_kernel(
    const unsigned short* __restrict__ QKV, float* __restrict__ part) {
  const int b = blockIdx.x >> 6;          // 0..7
  const int chunk = blockIdx.x & 63;      // 0..63 (16 rows each)
  const int t = threadIdx.x;
  float s0 = 0.f, s1 = 0.f;
  const unsigned short* p =
      QKV + ((size_t)(b * 1024 + chunk * 16)) * 1536 + 1024 + 2 * t;
  #pragma unroll 4
  for (int r = 0; r < 16; ++r) {
    const unsigned int w = *(const unsigned int*)p;
    s0 += b2f((unsigned short)(w & 0xffffu));
    s1 += b2f((unsigned short)(w >> 16));
    p += 1536;
  }
  float2 o; o.x = s0; o.y = s1;
  *(float2*)&part[(size_t)blockIdx.x * 512 + 2 * t] = o;
}

__global__ __launch_bounds__(256) void vsum2_kernel(
    const float* __restrict__ part, float* __restrict__ Vsum) {
  const int b = blockIdx.x;
  const int t = threadIdx.x;
  float s0 = 0.f, s1 = 0.f;
  const float* p = part + (size_t)b * 64 * 512;
  #pragma unroll
  for (int c = 0; c < 64; ++c) {
    s0 += p[(size_t)c * 512 + t];
    s1 += p[(size_t)c * 512 + t + 256];
  }
  Vsum[b * 512 + t] = s0;
  Vsum[b * 512 + t + 256] = s1;
}

// ---------------- band attention (closed-form softmax tail) ----------------
#define KVS 68
__global__ __launch_bounds__(256) void attn_kernel(
    const unsigned short* __restrict__ QKV, const float* __restrict__ Vsum,
    unsigned short* __restrict__ ctx) {
  __shared__ __align__(16) unsigned short Ks[130 * KVS];
  __shared__ __align__(16) unsigned short Vs[130 * KVS];
  __shared__ __align__(16) float vs_s[64];
  const int bh = blockIdx.x;              // 0..63
  const int b = bh >> 3, h = bh & 7;
  const int q0 = blockIdx.y * 128;        // 0..896
  const int t = threadIdx.x;
  const size_t rowb = ((size_t)b * 1024) * 1536;

  #pragma unroll
  for (int p = 0; p < 5; ++p) {
    const int i = p * 32 + (t >> 3);
    if (i < 130) {
      int g = q0 - 1 + i;
      g = g < 0 ? 0 : (g > 1023 ? 1023 : g);
      const unsigned short* src =
          QKV + rowb + (size_t)g * 1536 + h * 64 + (t & 7) * 8;
      const us8v kv = *(const us8v*)(src + 512);
      const us8v vv = *(const us8v*)(src + 1024);
      us4v lo, hi;
      #pragma unroll
      for (int r = 0; r < 4; ++r) { lo[r] = kv[r]; hi[r] = kv[r + 4]; }
      *(us4v*)&Ks[i * KVS + (t & 7) * 8]     = lo;
      *(us4v*)&Ks[i * KVS + (t & 7) * 8 + 4] = hi;
      #pragma unroll
      for (int r = 0; r < 4; ++r) { lo[r] = vv[r]; hi[r] = vv[r + 4]; }
      *(us4v*)&Vs[i * KVS + (t & 7) * 8]     = lo;
      *(us4v*)&Vs[i * KVS + (t & 7) * 8 + 4] = hi;
    }
  }
  if (t < 64) vs_s[t] = Vsum[(b << 9) + h * 64 + t];
  __syncthreads();

  const int q    = q0 + (t >> 1);
  const int half = t & 1;
  const int li   = (t >> 1) + 1;
  const int co   = half * 32;

  float pm = 0.f, p0 = 0.f, pp = 0.f;
  const unsigned short* Qp = QKV + rowb + (size_t)q * 1536 + h * 64 + co;
  const us8v qa = *(const us8v*)(Qp);
  const us8v qb = *(const us8v*)(Qp + 8);
  const us8v qc = *(const us8v*)(Qp + 16);
  const us8v qd = *(const us8v*)(Qp + 24);
  #pragma unroll
  for (int jj = 0; jj < 8; ++jj) {
    const us4v km = *(const us4v*)&Ks[(li - 1) * KVS + co + jj * 4];
    const us4v k0 = *(const us4v*)&Ks[li * KVS + co + jj * 4];
    const us4v kp = *(const us4v*)&Ks[(li + 1) * KVS + co + jj * 4];
    #pragma unroll
    for (int r = 0; r < 4; ++r) {
      const int e = jj * 4 + r;
      const unsigned short qu = (e < 8) ? qa[e & 7] : (e < 16) ? qb[e & 7]
                              : (e < 24) ? qc[e & 7] : qd[e & 7];
      const float qf = b2f(qu);
      pm += qf * b2f(km[r]);
      p0 += qf * b2f(k0[r]);
      pp += qf * b2f(kp[r]);
    }
  }
  pm += __shfl_xor(pm, 1);
  p0 += __shfl_xor(p0, 1);
  pp += __shfl_xor(pp, 1);

  const float OFF = -1e-9f;
  const float s0 = p0 * 0.125f;
  const float sm = (q > 0)    ? pm * 0.125f : OFF;
  const float sp = (q < 1023) ? pp * 0.125f : OFF;
  const float m  = fmaxf(fmaxf(s0, sm), fmaxf(sp, OFF));
  const float e0 = __expf(s0 - m), em = __expf(sm - m), ep = __expf(sp - m);
  const float eoff = __expf(OFF - m);
  const float inv  = 1.f / (e0 + em + ep + 1021.f * eoff);
  const float wm = (em - eoff) * inv, w0 = (e0 - eoff) * inv,
              wp = (ep - eoff) * inv, wt = eoff * inv;

  unsigned short* cp = ctx + ((size_t)(b * 1024 + q)) * 512 + h * 64 + co;
  #pragma unroll
  for (int jj = 0; jj < 8; ++jj) {
    const us4v a  = *(const us4v*)&Vs[(li - 1) * KVS + co + jj * 4];
    const us4v v0 = *(const us4v*)&Vs[li * KVS + co + jj * 4];
    const us4v c  = *(const us4v*)&Vs[(li + 1) * KVS + co + jj * 4];
    const float4 vsv = *(const float4*)&vs_s[co + jj * 4];
    us4v o;
    o[0] = f2b(wt * vsv.x + wm * b2f(a[0]) + w0 * b2f(v0[0]) + wp * b2f(c[0]));
    o[1] = f2b(wt * vsv.y + wm * b2f(a[1]) + w0 * b2f(v0[1]) + wp * b2f(c[1]));
    o[2] = f2b(wt * vsv.z + wm * b2f(a[2]) + w0 * b2f(v0[2]) + wp * b2f(c[2]));
    o[3] = f2b(wt * vsv.w + wm * b2f(a[3]) + w0 * b2f(v0[3]) + wp * b2f(c[3]));
    *(us4v*)(cp + jj * 4) = o;
  }
}

// ---------------- residual + LayerNorm over D=512 --------------------------
__global__ __launch_bounds__(256) void ln_kernel(
    const float* __restrict__ outp, const float* __restrict__ x,
    const float* __restrict__ gamma, const float* __restrict__ beta,
    float* __restrict__ y) {
  const int row = blockIdx.x;
  const int t = threadIdx.x;
  const size_t base = (size_t)row * 512;
  const float v0 = outp[base + t] + x[base + t];
  const float v1 = outp[base + t + 256] + x[base + t + 256];
  float s1 = v0 + v1;
  float s2 = v0 * v0 + v1 * v1;
  #pragma unroll
  for (int off = 32; off > 0; off >>= 1) {
    s1 += __shfl_xor(s1, off);
    s2 += __shfl_xor(s2, off);
  }
  __shared__ float r1[4], r2[4];
  const int wave = t >> 6, lane = t & 63;
  if (lane == 0) { r1[wave] = s1; r2[wave] = s2; }
  __syncthreads();
  s1 = r1[0] + r1[1] + r1[2] + r1[3];
  s2 = r2[0] + r2[1] + r2[2] + r2[3];
  const float mu  = s1 * (1.f / 512.f);
  const float var = s2 * (1.f / 512.f) - mu * mu;
  const float rs  = rsqrtf(var + 1e-5f);
  y[base + t]       = (v0 - mu) * rs * gamma[t]       + beta[t];
  y[base + t + 256] = (v1 - mu) * rs * gamma[t + 256] + beta[t + 256];
}

// ---------------------------------------------------------------------------
extern "C" void kernel_launch(void* const* d_in, const int* in_sizes, int n_in,
                              void* d_out, int out_size, void* d_ws, size_t ws_size,
                              hipStream_t stream) {
  const float* x     = (const float*)d_in[0];
  const float* Wq    = (const float*)d_in[1];
  const float* Wk    = (const float*)d_in[2];
  const float* Wv    = (const float*)d_in[3];
  const float* Wfc   = (const float*)d_in[4];
  const float* gamma = (const float*)d_in[5];
  const float* beta  = (const float*)d_in[6];
  float* y = (float*)d_out;

  char* ws = (char*)d_ws;
  unsigned short* Wt   = (unsigned short*)(ws);              // 2 MiB
  unsigned short* xb   = (unsigned short*)(ws + 2097152);    // 8 MiB
  unsigned short* QKV  = (unsigned short*)(ws + 10485760);   // 24 MiB
  float*          Vsum = (float*)(ws + 35651584);            // 16 KiB
  unsigned short* ctx  = (unsigned short*)(ws + 35667968);   // 8 MiB
  float*          outb = (float*)(ws + 44056576);            // 16 MiB
  float*          vpar = outb;  // 1 MiB partials, consumed before GEMM2

  wconv_kernel<<<dim3(16, 16, 4), 256, 0, stream>>>(Wq, Wk, Wv, Wfc, Wt);
  xconv_kernel<<<4096, 256, 0, stream>>>(x, xb);
  gemm_kernel<1><<<dim3(1536 / BN, 8192 / BM), 256, 0, stream>>>(
      xb, Wt, (void*)QKV, 8192, 1536, 512);
  vsum1_kernel<<<512, 256, 0, stream>>>(QKV, vpar);
  vsum2_kernel<<<8, 256, 0, stream>>>(vpar, Vsum);
  attn_kernel<<<dim3(64, 8), 256, 0, stream>>>(QKV, Vsum, ctx);
  gemm_kernel<0><<<dim3(512 / BN, 8192 / BM), 256, 0, stream>>>(
      ctx, Wt + (size_t)1536 * 512, (void*)outb, 8192, 512, 512);
  ln_kernel<<<8192, 256, 0, stream>>>(outb, x, gamma, beta, y);
}

// Round 5
// 136.822 us; speedup vs baseline: 1.7266x; 1.0739x over previous
//
#include <hip/hip_runtime.h>
#include <math.h>

// ---------------------------------------------------------------------------
// MultiAttention: x[8,1024,512] -> QKV proj (bf16 MFMA, fused V-colsum)
// -> tridiagonal-band "softmax" (off-band score=-1e-9 => uniform tail +
// 3-term band correction) -> FC GEMM fused with residual + LayerNorm.
// 4 launches total. GEMM staging: global_load_lds dwordx4, XOR-swizzled
// source so fragment ds_read_b128 is 2-way/bank (free).
// ---------------------------------------------------------------------------

typedef short     s8v  __attribute__((ext_vector_type(8)));   // 8 bf16
typedef float     f4v  __attribute__((ext_vector_type(4)));
typedef unsigned short us4v __attribute__((ext_vector_type(4)));
typedef unsigned short us8v __attribute__((ext_vector_type(8)));

__device__ __forceinline__ unsigned short f2b(float f) {
  union { float f; unsigned int u; } v; v.f = f;
  unsigned int u = v.u;
  return (unsigned short)((u + 0x7fffu + ((u >> 16) & 1u)) >> 16);  // RNE
}
__device__ __forceinline__ float b2f(unsigned short u) {
  union { unsigned int i; float f; } v; v.i = ((unsigned int)u) << 16;
  return v.f;
}
__device__ __forceinline__ void gload_lds16(const void* g, void* l) {
  __builtin_amdgcn_global_load_lds(
      (const __attribute__((address_space(1))) void*)g,
      (__attribute__((address_space(3))) void*)l, 16, 0, 0);
}

// ---------------- conv: x->bf16, W->bf16 transposed, Vsum=0 ----------------
// blocks 0..4095: xconv; 4096..5119: wconv; 5120: zero Vsum.
__global__ __launch_bounds__(256) void conv_kernel(
    const float* __restrict__ x,
    const float* __restrict__ Wq, const float* __restrict__ Wk,
    const float* __restrict__ Wv, const float* __restrict__ Wfc,
    unsigned short* __restrict__ xb, unsigned short* __restrict__ Wt,
    float* __restrict__ Vsum) {
  __shared__ unsigned short tile[32][33];
  const int bid = blockIdx.x, t = threadIdx.x;
  if (bid < 4096) {
    const int i = bid * 256 + t;
    const float4 f = ((const float4*)x)[i];
    us4v o; o[0] = f2b(f.x); o[1] = f2b(f.y); o[2] = f2b(f.z); o[3] = f2b(f.w);
    ((us4v*)xb)[i] = o;
  } else if (bid < 5120) {
    const int id = bid - 4096;
    const int z = id >> 8, rem = id & 255;
    const int bx = rem & 15, by = rem >> 4;
    const float* W = (z == 0) ? Wq : (z == 1) ? Wk : (z == 2) ? Wv : Wfc;
    const int tx = t & 31, ty = t >> 5;
    const int n0 = bx * 32, k0 = by * 32;
    #pragma unroll
    for (int r = ty; r < 32; r += 8)
      tile[r][tx] = f2b(W[(size_t)(k0 + r) * 512 + n0 + tx]);
    __syncthreads();
    unsigned short* dst = Wt + (size_t)z * 512 * 512;
    #pragma unroll
    for (int r = ty; r < 32; r += 8)
      dst[(size_t)(n0 + r) * 512 + k0 + tx] = tile[tx][r];
  } else {
    float4 zz = {0.f, 0.f, 0.f, 0.f};
    #pragma unroll
    for (int p = 0; p < 4; ++p) ((float4*)Vsum)[p * 256 + t] = zz;
  }
}

// ---------------- QKV GEMM (bf16 out) + fused V column sums ----------------
// C[8192,1536] = A[8192,512] * Bt[1536,512]^T; V-cols (bn>=1024) also
// atomicAdd fp32 column sums into Vsum[b*512 + col-1024].
#define BM 128
#define BN 128
#define BK 32

__global__ __launch_bounds__(256) void gemm_qkv_kernel(
    const unsigned short* __restrict__ A, const unsigned short* __restrict__ Bt,
    unsigned short* __restrict__ C, float* __restrict__ Vsum) {
  const int M = 8192, N = 1536, K = 512;
  __shared__ __align__(16) unsigned short smem[16384];
  unsigned short* As = smem;          // 4096 = 128x32
  unsigned short* Bs = smem + 4096;
  const int t    = threadIdx.x;
  const int wave = t >> 6, lane = t & 63;
  const int wr   = wave >> 1, wc = wave & 1;
  const int quad = lane >> 4, l16 = lane & 15;
  const int bm = blockIdx.y * BM, bn = blockIdx.x * BN;

  const int ci0 = wave * 128 + lane, ci1 = ci0 + 64;
  const int r0 = ci0 >> 2, c0 = (ci0 & 3) ^ ((r0 >> 1) & 3);
  const int r1 = ci1 >> 2, c1 = (ci1 & 3) ^ ((r1 >> 1) & 3);
  const unsigned short* ga0 = A  + (size_t)(bm + r0) * K + c0 * 8;
  const unsigned short* ga1 = A  + (size_t)(bm + r1) * K + c1 * 8;
  const unsigned short* gb0 = Bt + (size_t)(bn + r0) * K + c0 * 8;
  const unsigned short* gb1 = Bt + (size_t)(bn + r1) * K + c1 * 8;
  unsigned short* la0 = As + wave * 1024;
  unsigned short* la1 = As + wave * 1024 + 512;
  unsigned short* lb0 = Bs + wave * 1024;
  unsigned short* lb1 = Bs + wave * 1024 + 512;

  const int sw = (l16 >> 1) & 3;

  f4v acc[4][4];
  #pragma unroll
  for (int i = 0; i < 4; ++i)
    #pragma unroll
    for (int j = 0; j < 4; ++j) {
      f4v z = {0.f, 0.f, 0.f, 0.f};
      acc[i][j] = z;
    }

  for (int kt = 0; kt < K; kt += BK) {
    gload_lds16(ga0 + kt, la0);
    gload_lds16(ga1 + kt, la1);
    gload_lds16(gb0 + kt, lb0);
    gload_lds16(gb1 + kt, lb1);
    __syncthreads();

    s8v af[4], bf[4];
    #pragma unroll
    for (int i = 0; i < 4; ++i) {
      const int r = wr * 64 + i * 16 + l16;
      af[i] = *(const s8v*)&As[(r * 4 + (quad ^ sw)) * 8];
    }
    #pragma unroll
    for (int j = 0; j < 4; ++j) {
      const int r = wc * 64 + j * 16 + l16;
      bf[j] = *(const s8v*)&Bs[(r * 4 + (quad ^ sw)) * 8];
    }
    #pragma unroll
    for (int i = 0; i < 4; ++i)
      #pragma unroll
      for (int j = 0; j < 4; ++j)
        acc[i][j] = __builtin_amdgcn_mfma_f32_16x16x32_bf16(
            af[i], bf[j], acc[i][j], 0, 0, 0);
    __syncthreads();
  }

  // fused V column sums (fp32 acc, quad-reduced, atomic per column)
  if (bn >= 1024) {
    const int b = bm >> 10;
    #pragma unroll
    for (int j = 0; j < 4; ++j) {
      float ps = 0.f;
      #pragma unroll
      for (int i = 0; i < 4; ++i)
        #pragma unroll
        for (int r = 0; r < 4; ++r) ps += acc[i][j][r];
      ps += __shfl_xor(ps, 16);
      ps += __shfl_xor(ps, 32);
      if (quad == 0)
        atomicAdd(&Vsum[b * 512 + (bn - 1024) + wc * 64 + j * 16 + l16], ps);
    }
  }

  // bf16 C via LDS bounce -> coalesced 16B stores
  #pragma unroll
  for (int i = 0; i < 4; ++i) {
    const int lr0 = wr * 64 + i * 16 + quad * 4;
    #pragma unroll
    for (int j = 0; j < 4; ++j) {
      const int lc = wc * 64 + j * 16 + l16;
      #pragma unroll
      for (int r = 0; r < 4; ++r)
        smem[(lr0 + r) * 128 + lc] = f2b(acc[i][j][r]);
    }
  }
  __syncthreads();
  #pragma unroll
  for (int p = 0; p < 8; ++p) {
    const int row = p * 16 + (t >> 4);
    const int ch  = t & 15;
    *(us8v*)(C + (size_t)(bm + row) * N + bn + ch * 8) =
        *(const us8v*)&smem[row * 128 + ch * 8];
  }
}

// ---------------- band attention (closed-form softmax tail) ----------------
#define KVS 68
__global__ __launch_bounds__(256) void attn_kernel(
    const unsigned short* __restrict__ QKV, const float* __restrict__ Vsum,
    unsigned short* __restrict__ ctx) {
  __shared__ __align__(16) unsigned short Ks[130 * KVS];
  __shared__ __align__(16) unsigned short Vs[130 * KVS];
  __shared__ __align__(16) float vs_s[64];
  const int bh = blockIdx.x;
  const int b = bh >> 3, h = bh & 7;
  const int q0 = blockIdx.y * 128;
  const int t = threadIdx.x;
  const size_t rowb = ((size_t)b * 1024) * 1536;

  #pragma unroll
  for (int p = 0; p < 5; ++p) {
    const int i = p * 32 + (t >> 3);
    if (i < 130) {
      int g = q0 - 1 + i;
      g = g < 0 ? 0 : (g > 1023 ? 1023 : g);
      const unsigned short* src =
          QKV + rowb + (size_t)g * 1536 + h * 64 + (t & 7) * 8;
      const us8v kv = *(const us8v*)(src + 512);
      const us8v vv = *(const us8v*)(src + 1024);
      us4v lo, hi;
      #pragma unroll
      for (int r = 0; r < 4; ++r) { lo[r] = kv[r]; hi[r] = kv[r + 4]; }
      *(us4v*)&Ks[i * KVS + (t & 7) * 8]     = lo;
      *(us4v*)&Ks[i * KVS + (t & 7) * 8 + 4] = hi;
      #pragma unroll
      for (int r = 0; r < 4; ++r) { lo[r] = vv[r]; hi[r] = vv[r + 4]; }
      *(us4v*)&Vs[i * KVS + (t & 7) * 8]     = lo;
      *(us4v*)&Vs[i * KVS + (t & 7) * 8 + 4] = hi;
    }
  }
  if (t < 64) vs_s[t] = Vsum[(b << 9) + h * 64 + t];
  __syncthreads();

  const int q    = q0 + (t >> 1);
  const int half = t & 1;
  const int li   = (t >> 1) + 1;
  const int co   = half * 32;

  float pm = 0.f, p0 = 0.f, pp = 0.f;
  const unsigned short* Qp = QKV + rowb + (size_t)q * 1536 + h * 64 + co;
  const us8v qa = *(const us8v*)(Qp);
  const us8v qb = *(const us8v*)(Qp + 8);
  const us8v qc = *(const us8v*)(Qp + 16);
  const us8v qd = *(const us8v*)(Qp + 24);
  #pragma unroll
  for (int jj = 0; jj < 8; ++jj) {
    const us4v km = *(const us4v*)&Ks[(li - 1) * KVS + co + jj * 4];
    const us4v k0 = *(const us4v*)&Ks[li * KVS + co + jj * 4];
    const us4v kp = *(const us4v*)&Ks[(li + 1) * KVS + co + jj * 4];
    #pragma unroll
    for (int r = 0; r < 4; ++r) {
      const int e = jj * 4 + r;
      const unsigned short qu = (e < 8) ? qa[e & 7] : (e < 16) ? qb[e & 7]
                              : (e < 24) ? qc[e & 7] : qd[e & 7];
      const float qf = b2f(qu);
      pm += qf * b2f(km[r]);
      p0 += qf * b2f(k0[r]);
      pp += qf * b2f(kp[r]);
    }
  }
  pm += __shfl_xor(pm, 1);
  p0 += __shfl_xor(p0, 1);
  pp += __shfl_xor(pp, 1);

  const float OFF = -1e-9f;
  const float s0 = p0 * 0.125f;
  const float sm = (q > 0)    ? pm * 0.125f : OFF;
  const float sp = (q < 1023) ? pp * 0.125f : OFF;
  const float m  = fmaxf(fmaxf(s0, sm), fmaxf(sp, OFF));
  const float e0 = __expf(s0 - m), em = __expf(sm - m), ep = __expf(sp - m);
  const float eoff = __expf(OFF - m);
  const float inv  = 1.f / (e0 + em + ep + 1021.f * eoff);
  const float wm = (em - eoff) * inv, w0 = (e0 - eoff) * inv,
              wp = (ep - eoff) * inv, wt = eoff * inv;

  unsigned short* cp = ctx + ((size_t)(b * 1024 + q)) * 512 + h * 64 + co;
  #pragma unroll
  for (int jj = 0; jj < 8; ++jj) {
    const us4v a  = *(const us4v*)&Vs[(li - 1) * KVS + co + jj * 4];
    const us4v v0 = *(const us4v*)&Vs[li * KVS + co + jj * 4];
    const us4v c  = *(const us4v*)&Vs[(li + 1) * KVS + co + jj * 4];
    const float4 vsv = *(const float4*)&vs_s[co + jj * 4];
    us4v o;
    o[0] = f2b(wt * vsv.x + wm * b2f(a[0]) + w0 * b2f(v0[0]) + wp * b2f(c[0]));
    o[1] = f2b(wt * vsv.y + wm * b2f(a[1]) + w0 * b2f(v0[1]) + wp * b2f(c[1]));
    o[2] = f2b(wt * vsv.z + wm * b2f(a[2]) + w0 * b2f(v0[2]) + wp * b2f(c[2]));
    o[3] = f2b(wt * vsv.w + wm * b2f(a[3]) + w0 * b2f(v0[3]) + wp * b2f(c[3]));
    *(us4v*)(cp + jj * 4) = o;
  }
}

// ---------------- FC GEMM fused with residual + LayerNorm ------------------
// Block: 32 rows x all 512 cols; 512 threads = 8 waves (2 row x 4 col).
// out = ctx * Wfc^T; y = LN(out + x) * gamma + beta.  256 blocks (1/CU).
#define OS 516  // f32 row stride in LDS (2064 B, 16B aligned, de-banked)

__global__ __launch_bounds__(512) void gemm_fcln_kernel(
    const unsigned short* __restrict__ A,   // ctx [8192,512] bf16
    const unsigned short* __restrict__ Bt,  // Wfc^T [512,512] bf16
    const float* __restrict__ x, const float* __restrict__ gamma,
    const float* __restrict__ beta, float* __restrict__ y) {
  const int K = 512;
  __shared__ __align__(16) char smemraw[32 * OS * 4];  // 66 KB
  unsigned short* As = (unsigned short*)smemraw;        // 32x32 = 2 KB
  unsigned short* Bs = As + 1024;                       // 512x32 = 32 KB
  float* outS = (float*)smemraw;                        // epilogue alias

  const int t    = threadIdx.x;
  const int wave = t >> 6, lane = t & 63;
  const int wrr  = wave >> 2, wcc = wave & 3;  // 2 x 4
  const int quad = lane >> 4, l16 = lane & 15;
  const int bm = blockIdx.x * 32;
  const int sw = (l16 >> 1) & 3;

  // staging addresses
  // A: 128 chunks, waves 0-1 only
  const int cia = wave * 64 + lane;              // valid when wave<2
  const int ra = cia >> 2, ca = (cia & 3) ^ ((ra >> 1) & 3);
  const unsigned short* gA = A + (size_t)(bm + ra) * K + ca * 8;
  unsigned short* lA = As + wave * 512;
  // B: 2048 chunks, all 8 waves x 4 issues
  int rb[4], cb[4];
  #pragma unroll
  for (int p = 0; p < 4; ++p) {
    const int ci = wave * 256 + p * 64 + lane;
    rb[p] = ci >> 2; cb[p] = (ci & 3) ^ ((rb[p] >> 1) & 3);
  }
  unsigned short* lB = Bs + wave * 2048;

  f4v acc[8];
  #pragma unroll
  for (int j = 0; j < 8; ++j) {
    f4v z = {0.f, 0.f, 0.f, 0.f};
    acc[j] = z;
  }

  for (int kt = 0; kt < K; kt += BK) {
    if (wave < 2) gload_lds16(gA + kt, lA);
    #pragma unroll
    for (int p = 0; p < 4; ++p)
      gload_lds16(Bt + (size_t)rb[p] * K + kt + cb[p] * 8, lB + p * 512);
    __syncthreads();

    const int rm = wrr * 16 + l16;
    const s8v af = *(const s8v*)&As[(rm * 4 + (quad ^ sw)) * 8];
    #pragma unroll
    for (int j = 0; j < 8; ++j) {
      const int n = wcc * 128 + j * 16 + l16;
      const s8v bf = *(const s8v*)&Bs[(n * 4 + (quad ^ sw)) * 8];
      acc[j] = __builtin_amdgcn_mfma_f32_16x16x32_bf16(af, bf, acc[j], 0, 0, 0);
    }
    __syncthreads();
  }

  // acc -> LDS fp32 (row stride OS breaks bank alignment across quads)
  #pragma unroll
  for (int j = 0; j < 8; ++j) {
    const int col = wcc * 128 + j * 16 + l16;
    const int row0 = wrr * 16 + quad * 4;
    #pragma unroll
    for (int r = 0; r < 4; ++r)
      outS[(row0 + r) * OS + col] = acc[j][r];
  }
  __syncthreads();

  // residual + LN: 16 threads per row, each handles 8 float4 strided by 64
  const int row = t >> 4, l = t & 15;
  const size_t gbase = (size_t)(bm + row) * 512;
  float4 v[8];
  float s1 = 0.f, s2 = 0.f;
  #pragma unroll
  for (int k = 0; k < 8; ++k) {
    const int c = k * 64 + l * 4;
    const float4 a  = *(const float4*)&outS[row * OS + c];
    const float4 xv = *(const float4*)&x[gbase + c];
    float4 w;
    w.x = a.x + xv.x; w.y = a.y + xv.y; w.z = a.z + xv.z; w.w = a.w + xv.w;
    v[k] = w;
    s1 += w.x + w.y + w.z + w.w;
    s2 += w.x * w.x + w.y * w.y + w.z * w.z + w.w * w.w;
  }
  #pragma unroll
  for (int m = 1; m < 16; m <<= 1) {
    s1 += __shfl_xor(s1, m);
    s2 += __shfl_xor(s2, m);
  }
  const float mu  = s1 * (1.f / 512.f);
  const float var = s2 * (1.f / 512.f) - mu * mu;
  const float rs  = rsqrtf(var + 1e-5f);
  #pragma unroll
  for (int k = 0; k < 8; ++k) {
    const int c = k * 64 + l * 4;
    const float4 g  = *(const float4*)&gamma[c];
    const float4 bb = *(const float4*)&beta[c];
    float4 o;
    o.x = (v[k].x - mu) * rs * g.x + bb.x;
    o.y = (v[k].y - mu) * rs * g.y + bb.y;
    o.z = (v[k].z - mu) * rs * g.z + bb.z;
    o.w = (v[k].w - mu) * rs * g.w + bb.w;
    *(float4*)&y[gbase + c] = o;
  }
}

// ---------------------------------------------------------------------------
extern "C" void kernel_launch(void* const* d_in, const int* in_sizes, int n_in,
                              void* d_out, int out_size, void* d_ws, size_t ws_size,
                              hipStream_t stream) {
  const float* x     = (const float*)d_in[0];
  const float* Wq    = (const float*)d_in[1];
  const float* Wk    = (const float*)d_in[2];
  const float* Wv    = (const float*)d_in[3];
  const float* Wfc   = (const float*)d_in[4];
  const float* gamma = (const float*)d_in[5];
  const float* beta  = (const float*)d_in[6];
  float* y = (float*)d_out;

  char* ws = (char*)d_ws;
  unsigned short* Wt   = (unsigned short*)(ws);              // 2 MiB
  unsigned short* xb   = (unsigned short*)(ws + 2097152);    // 8 MiB
  unsigned short* QKV  = (unsigned short*)(ws + 10485760);   // 24 MiB
  float*          Vsum = (float*)(ws + 35651584);            // 16 KiB
  unsigned short* ctx  = (unsigned short*)(ws + 35667968);   // 8 MiB

  conv_kernel<<<5121, 256, 0, stream>>>(x, Wq, Wk, Wv, Wfc, xb, Wt, Vsum);
  gemm_qkv_kernel<<<dim3(12, 64), 256, 0, stream>>>(xb, Wt, QKV, Vsum);
  attn_kernel<<<dim3(64, 8), 256, 0, stream>>>(QKV, Vsum, ctx);
  gemm_fcln_kernel<<<256, 512, 0, stream>>>(
      ctx, Wt + (size_t)1536 * 512, x, gamma, beta, y);
}

// Round 6
// 128.101 us; speedup vs baseline: 1.8442x; 1.0681x over previous
//
#include <hip/hip_runtime.h>
#include <math.h>

// ---------------------------------------------------------------------------
// MultiAttention: x[8,1024,512] -> QKV proj (bf16 MFMA, fused V-colsum)
// -> tridiagonal-band "softmax" (off-band score=-1e-9 => uniform tail +
// 3-term band correction) -> FC GEMM fused with residual + LayerNorm.
// 4 launches. GEMMs: BK=64, global_load_lds dwordx4 with XOR-swizzled source
// (fragment ds_read_b128 lands 2-way/bank = free). fcln: LDS double-buffer,
// one barrier/iter, DMA issued under the MFMA chain (1 block/CU -> explicit
// overlap needed).
// ---------------------------------------------------------------------------

typedef short     s8v  __attribute__((ext_vector_type(8)));   // 8 bf16
typedef float     f4v  __attribute__((ext_vector_type(4)));
typedef unsigned short us4v __attribute__((ext_vector_type(4)));
typedef unsigned short us8v __attribute__((ext_vector_type(8)));

__device__ __forceinline__ unsigned short f2b(float f) {
  union { float f; unsigned int u; } v; v.f = f;
  unsigned int u = v.u;
  return (unsigned short)((u + 0x7fffu + ((u >> 16) & 1u)) >> 16);  // RNE
}
__device__ __forceinline__ float b2f(unsigned short u) {
  union { unsigned int i; float f; } v; v.i = ((unsigned int)u) << 16;
  return v.f;
}
__device__ __forceinline__ void gload_lds16(const void* g, void* l) {
  __builtin_amdgcn_global_load_lds(
      (const __attribute__((address_space(1))) void*)g,
      (__attribute__((address_space(3))) void*)l, 16, 0, 0);
}

// ---------------- conv: x->bf16, W->bf16 transposed, Vsum=0 ----------------
__global__ __launch_bounds__(256) void conv_kernel(
    const float* __restrict__ x,
    const float* __restrict__ Wq, const float* __restrict__ Wk,
    const float* __restrict__ Wv, const float* __restrict__ Wfc,
    unsigned short* __restrict__ xb, unsigned short* __restrict__ Wt,
    float* __restrict__ Vsum) {
  __shared__ unsigned short tile[32][33];
  const int bid = blockIdx.x, t = threadIdx.x;
  if (bid < 4096) {
    const int i = bid * 256 + t;
    const float4 f = ((const float4*)x)[i];
    us4v o; o[0] = f2b(f.x); o[1] = f2b(f.y); o[2] = f2b(f.z); o[3] = f2b(f.w);
    ((us4v*)xb)[i] = o;
  } else if (bid < 5120) {
    const int id = bid - 4096;
    const int z = id >> 8, rem = id & 255;
    const int bx = rem & 15, by = rem >> 4;
    const float* W = (z == 0) ? Wq : (z == 1) ? Wk : (z == 2) ? Wv : Wfc;
    const int tx = t & 31, ty = t >> 5;
    const int n0 = bx * 32, k0 = by * 32;
    #pragma unroll
    for (int r = ty; r < 32; r += 8)
      tile[r][tx] = f2b(W[(size_t)(k0 + r) * 512 + n0 + tx]);
    __syncthreads();
    unsigned short* dst = Wt + (size_t)z * 512 * 512;
    #pragma unroll
    for (int r = ty; r < 32; r += 8)
      dst[(size_t)(n0 + r) * 512 + k0 + tx] = tile[tx][r];
  } else {
    float4 zz = {0.f, 0.f, 0.f, 0.f};
    #pragma unroll
    for (int p = 0; p < 4; ++p) ((float4*)Vsum)[p * 256 + t] = zz;
  }
}

// ---------------- QKV GEMM (bf16 out, BK=64) + fused V column sums ---------
// C[8192,1536] = A[8192,512] * Bt[1536,512]^T.
// LDS slot (row r, chunk cs) holds global k-chunk cs^(r&7)  (16B chunks,
// 8 per row) => fragment reads (chunk quad+4s) are 2-way/bank.
__global__ __launch_bounds__(256) void gemm_qkv_kernel(
    const unsigned short* __restrict__ A, const unsigned short* __restrict__ Bt,
    unsigned short* __restrict__ C, float* __restrict__ Vsum) {
  const int N = 1536, K = 512;
  __shared__ __align__(16) unsigned short smem[16384];  // 32 KB
  unsigned short* As = smem;          // 128x64 = 8192 ush
  unsigned short* Bs = smem + 8192;
  const int t = threadIdx.x, wave = t >> 6, lane = t & 63;
  const int wr = wave >> 1, wc = wave & 1;
  const int quad = lane >> 4, l16 = lane & 15;
  const int bm = blockIdx.y * 128, bn = blockIdx.x * 128;

  const unsigned short *gA[4], *gB[4];
  #pragma unroll
  for (int p = 0; p < 4; ++p) {
    const int ci = wave * 256 + p * 64 + lane;
    const int r = ci >> 3, c = (ci & 7) ^ (r & 7);
    gA[p] = A + (size_t)(bm + r) * K + c * 8;
    gB[p] = Bt + (size_t)(bn + r) * K + c * 8;
  }

  f4v acc[4][4];
  #pragma unroll
  for (int i = 0; i < 4; ++i)
    #pragma unroll
    for (int j = 0; j < 4; ++j) {
      f4v z = {0.f, 0.f, 0.f, 0.f};
      acc[i][j] = z;
    }

  for (int kt = 0; kt < K; kt += 64) {
    #pragma unroll
    for (int p = 0; p < 4; ++p)
      gload_lds16(gA[p] + kt, As + wave * 2048 + p * 512);
    #pragma unroll
    for (int p = 0; p < 4; ++p)
      gload_lds16(gB[p] + kt, Bs + wave * 2048 + p * 512);
    __syncthreads();

    #pragma unroll
    for (int s = 0; s < 2; ++s) {
      s8v af[4], bf[4];
      #pragma unroll
      for (int i = 0; i < 4; ++i) {
        const int r = wr * 64 + i * 16 + l16;
        af[i] = *(const s8v*)&As[(r * 8 + ((quad + 4 * s) ^ (r & 7))) * 8];
      }
      #pragma unroll
      for (int j = 0; j < 4; ++j) {
        const int r = wc * 64 + j * 16 + l16;
        bf[j] = *(const s8v*)&Bs[(r * 8 + ((quad + 4 * s) ^ (r & 7))) * 8];
      }
      #pragma unroll
      for (int i = 0; i < 4; ++i)
        #pragma unroll
        for (int j = 0; j < 4; ++j)
          acc[i][j] = __builtin_amdgcn_mfma_f32_16x16x32_bf16(
              af[i], bf[j], acc[i][j], 0, 0, 0);
    }
    __syncthreads();
  }

  // fused V column sums (fp32 acc, quad-reduced, atomic per column)
  if (bn >= 1024) {
    const int b = bm >> 10;
    #pragma unroll
    for (int j = 0; j < 4; ++j) {
      float ps = 0.f;
      #pragma unroll
      for (int i = 0; i < 4; ++i)
        #pragma unroll
        for (int r = 0; r < 4; ++r) ps += acc[i][j][r];
      ps += __shfl_xor(ps, 16);
      ps += __shfl_xor(ps, 32);
      if (quad == 0)
        atomicAdd(&Vsum[b * 512 + (bn - 1024) + wc * 64 + j * 16 + l16], ps);
    }
  }

  // bf16 C via LDS bounce -> coalesced 16B stores
  #pragma unroll
  for (int i = 0; i < 4; ++i) {
    const int lr0 = wr * 64 + i * 16 + quad * 4;
    #pragma unroll
    for (int j = 0; j < 4; ++j) {
      const int lc = wc * 64 + j * 16 + l16;
      #pragma unroll
      for (int r = 0; r < 4; ++r)
        smem[(lr0 + r) * 128 + lc] = f2b(acc[i][j][r]);
    }
  }
  __syncthreads();
  #pragma unroll
  for (int p = 0; p < 8; ++p) {
    const int row = p * 16 + (t >> 4);
    const int ch  = t & 15;
    *(us8v*)(C + (size_t)(bm + row) * N + bn + ch * 8) =
        *(const us8v*)&smem[row * 128 + ch * 8];
  }
}

// ---------------- band attention (closed-form softmax tail) ----------------
// Q, K, V all LDS-staged (coalesced 128B row slices).
#define KVS 68
__global__ __launch_bounds__(256) void attn_kernel(
    const unsigned short* __restrict__ QKV, const float* __restrict__ Vsum,
    unsigned short* __restrict__ ctx) {
  __shared__ __align__(16) unsigned short Qs[130 * KVS];
  __shared__ __align__(16) unsigned short Ks[130 * KVS];
  __shared__ __align__(16) unsigned short Vs[130 * KVS];
  __shared__ __align__(16) float vs_s[64];
  const int bh = blockIdx.x;
  const int b = bh >> 3, h = bh & 7;
  const int q0 = blockIdx.y * 128;
  const int t = threadIdx.x;
  const size_t rowb = ((size_t)b * 1024) * 1536;

  #pragma unroll
  for (int p = 0; p < 5; ++p) {
    const int i = p * 32 + (t >> 3);
    if (i < 130) {
      int g = q0 - 1 + i;
      g = g < 0 ? 0 : (g > 1023 ? 1023 : g);
      const unsigned short* src =
          QKV + rowb + (size_t)g * 1536 + h * 64 + (t & 7) * 8;
      const us8v qv = *(const us8v*)(src);
      const us8v kv = *(const us8v*)(src + 512);
      const us8v vv = *(const us8v*)(src + 1024);
      us4v lo, hi;
      #pragma unroll
      for (int r = 0; r < 4; ++r) { lo[r] = qv[r]; hi[r] = qv[r + 4]; }
      *(us4v*)&Qs[i * KVS + (t & 7) * 8]     = lo;
      *(us4v*)&Qs[i * KVS + (t & 7) * 8 + 4] = hi;
      #pragma unroll
      for (int r = 0; r < 4; ++r) { lo[r] = kv[r]; hi[r] = kv[r + 4]; }
      *(us4v*)&Ks[i * KVS + (t & 7) * 8]     = lo;
      *(us4v*)&Ks[i * KVS + (t & 7) * 8 + 4] = hi;
      #pragma unroll
      for (int r = 0; r < 4; ++r) { lo[r] = vv[r]; hi[r] = vv[r + 4]; }
      *(us4v*)&Vs[i * KVS + (t & 7) * 8]     = lo;
      *(us4v*)&Vs[i * KVS + (t & 7) * 8 + 4] = hi;
    }
  }
  if (t < 64) vs_s[t] = Vsum[(b << 9) + h * 64 + t];
  __syncthreads();

  const int q    = q0 + (t >> 1);
  const int half = t & 1;
  const int li   = (t >> 1) + 1;
  const int co   = half * 32;

  float pm = 0.f, p0 = 0.f, pp = 0.f;
  #pragma unroll
  for (int jj = 0; jj < 8; ++jj) {
    const us4v qv = *(const us4v*)&Qs[li * KVS + co + jj * 4];
    const us4v km = *(const us4v*)&Ks[(li - 1) * KVS + co + jj * 4];
    const us4v k0 = *(const us4v*)&Ks[li * KVS + co + jj * 4];
    const us4v kp = *(const us4v*)&Ks[(li + 1) * KVS + co + jj * 4];
    #pragma unroll
    for (int r = 0; r < 4; ++r) {
      const float qf = b2f(qv[r]);
      pm += qf * b2f(km[r]);
      p0 += qf * b2f(k0[r]);
      pp += qf * b2f(kp[r]);
    }
  }
  pm += __shfl_xor(pm, 1);
  p0 += __shfl_xor(p0, 1);
  pp += __shfl_xor(pp, 1);

  const float OFF = -1e-9f;
  const float s0 = p0 * 0.125f;
  const float sm = (q > 0)    ? pm * 0.125f : OFF;
  const float sp = (q < 1023) ? pp * 0.125f : OFF;
  const float m  = fmaxf(fmaxf(s0, sm), fmaxf(sp, OFF));
  const float e0 = __expf(s0 - m), em = __expf(sm - m), ep = __expf(sp - m);
  const float eoff = __expf(OFF - m);
  const float inv  = 1.f / (e0 + em + ep + 1021.f * eoff);
  const float wm = (em - eoff) * inv, w0 = (e0 - eoff) * inv,
              wp = (ep - eoff) * inv, wt = eoff * inv;

  unsigned short* cp = ctx + ((size_t)(b * 1024 + q)) * 512 + h * 64 + co;
  #pragma unroll
  for (int jj = 0; jj < 8; ++jj) {
    const us4v a  = *(const us4v*)&Vs[(li - 1) * KVS + co + jj * 4];
    const us4v v0 = *(const us4v*)&Vs[li * KVS + co + jj * 4];
    const us4v c  = *(const us4v*)&Vs[(li + 1) * KVS + co + jj * 4];
    const float4 vsv = *(const float4*)&vs_s[co + jj * 4];
    us4v o;
    o[0] = f2b(wt * vsv.x + wm * b2f(a[0]) + w0 * b2f(v0[0]) + wp * b2f(c[0]));
    o[1] = f2b(wt * vsv.y + wm * b2f(a[1]) + w0 * b2f(v0[1]) + wp * b2f(c[1]));
    o[2] = f2b(wt * vsv.z + wm * b2f(a[2]) + w0 * b2f(v0[2]) + wp * b2f(c[2]));
    o[3] = f2b(wt * vsv.w + wm * b2f(a[3]) + w0 * b2f(v0[3]) + wp * b2f(c[3]));
    *(us4v*)(cp + jj * 4) = o;
  }
}

// ---------------- FC GEMM fused with residual + LayerNorm ------------------
// Block: 32 rows x 512 cols; 512 threads = 8 waves (2 row-groups x 4 col).
// BK=64, LDS double-buffered (68 KB x2), ONE barrier per iter; next-tile DMA
// issued under the MFMA chain (1 block/CU => explicit overlap required).
#define OS 516  // f32 row stride in LDS epilogue

__global__ __launch_bounds__(512) void gemm_fcln_kernel(
    const unsigned short* __restrict__ A,   // ctx [8192,512] bf16
    const unsigned short* __restrict__ Bt,  // Wfc^T [512,512] bf16
    const unsigned short* __restrict__ xb, const float* __restrict__ gamma,
    const float* __restrict__ beta, float* __restrict__ y) {
  const int K = 512;
  // buffer: A 32x64 = 2048 ush, B 512x64 = 32768 ush -> 34816 ush; x2 = 136 KB
  __shared__ __align__(16) unsigned short smem[69632];
  float* outS = (float*)smem;

  const int t = threadIdx.x, wave = t >> 6, lane = t & 63;
  const int wrr = wave >> 2, wcc = wave & 3;
  const int quad = lane >> 4, l16 = lane & 15;
  const int bm = blockIdx.x * 32;

  // A staging: 256 chunks, waves 0..3 one instr each
  const int ciA = wave * 64 + lane;
  const int rA = ciA >> 3, cA = (ciA & 7) ^ (rA & 7);
  const unsigned short* gA = A + (size_t)(bm + rA) * K + cA * 8;
  // B staging: 4096 chunks, 8 instrs per wave
  const unsigned short* gB[8];
  #pragma unroll
  for (int p = 0; p < 8; ++p) {
    const int ci = wave * 512 + p * 64 + lane;
    const int r = ci >> 3, c = (ci & 7) ^ (r & 7);
    gB[p] = Bt + (size_t)r * K + c * 8;
  }

  f4v acc[8];
  #pragma unroll
  for (int j = 0; j < 8; ++j) {
    f4v z = {0.f, 0.f, 0.f, 0.f};
    acc[j] = z;
  }

  // prologue: stage k-tile 0 into buffer 0
  if (wave < 4) gload_lds16(gA, smem + wave * 512);
  #pragma unroll
  for (int p = 0; p < 8; ++p)
    gload_lds16(gB[p], smem + 2048 + wave * 4096 + p * 512);
  __syncthreads();

  for (int it = 0; it < 8; ++it) {
    const int cur = (it & 1) * 34816;
    const int nxt = 34816 - cur;
    const unsigned short* Ab = smem + cur;
    const unsigned short* Bb = smem + cur + 2048;
    const int rm = wrr * 16 + l16;
    const s8v af0 = *(const s8v*)&Ab[(rm * 8 + (quad ^ (rm & 7))) * 8];
    const s8v af1 = *(const s8v*)&Ab[(rm * 8 + ((quad + 4) ^ (rm & 7))) * 8];
    s8v bf0[8];
    #pragma unroll
    for (int j = 0; j < 8; ++j) {
      const int n = wcc * 128 + j * 16 + l16;
      bf0[j] = *(const s8v*)&Bb[(n * 8 + (quad ^ (n & 7))) * 8];
    }
    if (it < 7) {  // DMA next tile; runs under the MFMA chain
      const int kt = (it + 1) * 64;
      if (wave < 4) gload_lds16(gA + kt, smem + nxt + wave * 512);
      #pragma unroll
      for (int p = 0; p < 8; ++p)
        gload_lds16(gB[p] + kt, smem + nxt + 2048 + wave * 4096 + p * 512);
    }
    #pragma unroll
    for (int j = 0; j < 8; ++j)
      acc[j] = __builtin_amdgcn_mfma_f32_16x16x32_bf16(af0, bf0[j], acc[j], 0, 0, 0);
    #pragma unroll
    for (int j = 0; j < 8; ++j) {
      const int n = wcc * 128 + j * 16 + l16;
      const s8v bf1 = *(const s8v*)&Bb[(n * 8 + ((quad + 4) ^ (n & 7))) * 8];
      acc[j] = __builtin_amdgcn_mfma_f32_16x16x32_bf16(af1, bf1, acc[j], 0, 0, 0);
    }
    __syncthreads();  // drains reads of cur + DMA into nxt
  }

  // acc -> LDS fp32
  #pragma unroll
  for (int j = 0; j < 8; ++j) {
    const int col = wcc * 128 + j * 16 + l16;
    const int row0 = wrr * 16 + quad * 4;
    #pragma unroll
    for (int r = 0; r < 4; ++r)
      outS[(row0 + r) * OS + col] = acc[j][r];
  }
  __syncthreads();

  // residual (bf16 xb) + LN: 16 threads per row
  const int row = t >> 4, l = t & 15;
  const size_t gbase = (size_t)(bm + row) * 512;
  float4 v[8];
  float s1 = 0.f, s2 = 0.f;
  #pragma unroll
  for (int k = 0; k < 8; ++k) {
    const int c = k * 64 + l * 4;
    const float4 a = *(const float4*)&outS[row * OS + c];
    const us4v xv = *(const us4v*)&xb[gbase + c];
    float4 w;
    w.x = a.x + b2f(xv[0]); w.y = a.y + b2f(xv[1]);
    w.z = a.z + b2f(xv[2]); w.w = a.w + b2f(xv[3]);
    v[k] = w;
    s1 += w.x + w.y + w.z + w.w;
    s2 += w.x * w.x + w.y * w.y + w.z * w.z + w.w * w.w;
  }
  #pragma unroll
  for (int m = 1; m < 16; m <<= 1) {
    s1 += __shfl_xor(s1, m);
    s2 += __shfl_xor(s2, m);
  }
  const float mu  = s1 * (1.f / 512.f);
  const float var = s2 * (1.f / 512.f) - mu * mu;
  const float rs  = rsqrtf(var + 1e-5f);
  #pragma unroll
  for (int k = 0; k < 8; ++k) {
    const int c = k * 64 + l * 4;
    const float4 g  = *(const float4*)&gamma[c];
    const float4 bb = *(const float4*)&beta[c];
    float4 o;
    o.x = (v[k].x - mu) * rs * g.x + bb.x;
    o.y = (v[k].y - mu) * rs * g.y + bb.y;
    o.z = (v[k].z - mu) * rs * g.z + bb.z;
    o.w = (v[k].w - mu) * rs * g.w + bb.w;
    *(float4*)&y[gbase + c] = o;
  }
}

// ---------------------------------------------------------------------------
extern "C" void kernel_launch(void* const* d_in, const int* in_sizes, int n_in,
                              void* d_out, int out_size, void* d_ws, size_t ws_size,
                              hipStream_t stream) {
  const float* x     = (const float*)d_in[0];
  const float* Wq    = (const float*)d_in[1];
  const float* Wk    = (const float*)d_in[2];
  const float* Wv    = (const float*)d_in[3];
  const float* Wfc   = (const float*)d_in[4];
  const float* gamma = (const float*)d_in[5];
  const float* beta  = (const float*)d_in[6];
  float* y = (float*)d_out;

  char* ws = (char*)d_ws;
  unsigned short* Wt   = (unsigned short*)(ws);              // 2 MiB
  unsigned short* xb   = (unsigned short*)(ws + 2097152);    // 8 MiB
  unsigned short* QKV  = (unsigned short*)(ws + 10485760);   // 24 MiB
  float*          Vsum = (float*)(ws + 35651584);            // 16 KiB
  unsigned short* ctx  = (unsigned short*)(ws + 35667968);   // 8 MiB

  conv_kernel<<<5121, 256, 0, stream>>>(x, Wq, Wk, Wv, Wfc, xb, Wt, Vsum);
  gemm_qkv_kernel<<<dim3(12, 64), 256, 0, stream>>>(xb, Wt, QKV, Vsum);
  attn_kernel<<<dim3(64, 8), 256, 0, stream>>>(QKV, Vsum, ctx);
  gemm_fcln_kernel<<<256, 512, 0, stream>>>(
      ctx, Wt + (size_t)1536 * 512, xb, gamma, beta, y);
}